// Round 10
// baseline (343.496 us; speedup 1.0000x reference)
//
#include <hip/hip_runtime.h>
#include <hip/hip_bf16.h>

typedef __hip_bfloat16 bf16;
typedef __bf16 bf16x8 __attribute__((ext_vector_type(8)));
typedef float f32x4 __attribute__((ext_vector_type(4)));

#define LQ 1024
#define SK 1024
#define MMEM 256
#define NB 8
#define EE 512
#define NH 8
#define HD 64
#define NBH 64  // NB*NH batched (n,h) pairs

__device__ inline __bf16 tobf(float f) {
  __hip_bfloat16 h = __float2bfloat16(f);
  return *reinterpret_cast<__bf16*>(&h);
}
__device__ inline float bf2f(__bf16 x) {
  unsigned short u; __builtin_memcpy(&u, &x, 2);
  unsigned int v = (unsigned int)u << 16;
  float f; __builtin_memcpy(&f, &v, 4);
  return f;
}
__device__ inline f32x4 MFMA(bf16x8 a, bf16x8 b, f32x4 c) {
  return __builtin_amdgcn_mfma_f32_16x16x32_bf16(a, b, c, 0, 0, 0);
}

// async global->LDS, 16B per lane. LDS dest is wave-uniform base + lane*16.
__device__ inline void gload_lds16(const bf16* g, void* l) {
  __builtin_amdgcn_global_load_lds(
      (const __attribute__((address_space(1))) void*)g,
      (__attribute__((address_space(3))) void*)l, 16, 0, 0);
}

__device__ inline bf16x8 load8(const float* p) {
  float4 a = *(const float4*)p;
  float4 b = *(const float4*)(p + 4);
  bf16x8 r;
  r[0] = tobf(a.x); r[1] = tobf(a.y); r[2] = tobf(a.z); r[3] = tobf(a.w);
  r[4] = tobf(b.x); r[5] = tobf(b.y); r[6] = tobf(b.z); r[7] = tobf(b.w);
  return r;
}

// ================= bf16 pre-conversion of GEMM inputs ============================
#define CVT_T0 524288   // threads per q/k/v region (8 elems each)
#define CVT_T3 98304    // ipw
#define CVT_T4 32768    // opw
__global__ __launch_bounds__(256) void convert5(
    const float* __restrict__ q, const float* __restrict__ k,
    const float* __restrict__ v, const float* __restrict__ w,
    const float* __restrict__ o, bf16* __restrict__ qc, bf16* __restrict__ kc,
    bf16* __restrict__ vc, bf16* __restrict__ wc, bf16* __restrict__ oc)
{
  long long t = (long long)blockIdx.x * 256 + threadIdx.x;
  const float* src; bf16* dst; long long idx;
  if (t < CVT_T0)               { src = q; dst = qc; idx = t; }
  else if (t < 2 * CVT_T0)      { src = k; dst = kc; idx = t - CVT_T0; }
  else if (t < 3 * CVT_T0)      { src = v; dst = vc; idx = t - 2 * CVT_T0; }
  else if (t < 3 * CVT_T0 + CVT_T3) { src = w; dst = wc; idx = t - 3 * CVT_T0; }
  else                          { src = o; dst = oc; idx = t - 3 * CVT_T0 - CVT_T3; }
  *(bf16x8*)(dst + idx * 8) = load8(src + idx * 8);
}

// ================= 3-in-1 projection GEMM, m97-structure, PURE GEMM ==============
// z=0 alpha folds log2e so downstream softmax uses native exp2 (saves one v_mul
// per exp in colsum + attn, all mathematically identical: exp(S)=2^(S*log2e)).
__global__ __launch_bounds__(256) void gemm_proj3(
    const bf16* __restrict__ qc, const bf16* __restrict__ kc,
    const bf16* __restrict__ vc, const bf16* __restrict__ ipwb,
    const float* __restrict__ ipb, bf16* __restrict__ pq,
    bf16* __restrict__ pk, bf16* __restrict__ v_raw)
{
  __shared__ __align__(16) char smem[33792];
  __bf16* As = (__bf16*)smem;             // [128][64] linear, 16384 B
  __bf16* Bs = (__bf16*)(smem + 16384);   // [128][64] linear, 16384 B
  const int z = blockIdx.z;
  const bf16* A = (z == 0) ? qc : (z == 1) ? kc : vc;
  const bf16* W = ipwb + (long long)z * EE * EE;
  const float* bias = ipb + z * EE;
  const float alpha = (z == 0) ? 0.1803368801f : 1.f;  // 0.125 * log2(e)
  const int bid2 = blockIdx.y * gridDim.x + blockIdx.x;
  const int xcd = bid2 & 7, sub = bid2 >> 3;       // sub in [0,32)
  const int by = (xcd << 3) + (sub >> 2);          // 0..63
  const int bx = sub & 3;                          // 0..3
  const int tm0 = by << 7, tn0 = bx << 7;          // 128 x 128
  const int t = threadIdx.x;
  const int wave = t >> 6, lane = t & 63;
  const int wrow0 = (wave & 1) << 6, wcol0 = (wave >> 1) << 6;
  const int m16 = lane & 15, quad = lane >> 4;

  const f32x4 zero = {0.f, 0.f, 0.f, 0.f};
  f32x4 acc[4][4];
#pragma unroll
  for (int mi = 0; mi < 4; ++mi)
#pragma unroll
    for (int ni = 0; ni < 4; ++ni) acc[mi][ni] = zero;

  const bf16* Ab = A + (long long)tm0 * EE;
  const bf16* Bb = W + (long long)tn0 * EE;
  const int ob_u = wave << 10;  // wave-uniform byte base within 4KB chunk

  for (int k0 = 0; k0 < EE; k0 += 64) {
#pragma unroll
    for (int c = 0; c < 4; ++c) {
      int ob = (c << 12) + ob_u;          // uniform LDS byte base
      int obl = ob + (lane << 4);         // this lane's slot
      int row = obl >> 7;                 // tile row (stride 128 B)
      int ce = (obl & 127) >> 1;          // element within row
      gload_lds16(Ab + (long long)row * EE + k0 + ce, smem + ob);
      gload_lds16(Bb + (long long)row * EE + k0 + ce, smem + 16384 + ob);
    }
    __syncthreads();
#pragma unroll
    for (int kh = 0; kh < 2; ++kh) {
      bf16x8 av[4], bv[4];
#pragma unroll
      for (int i = 0; i < 4; ++i) {
        av[i] = *(bf16x8*)(As + ((wrow0 + (i << 4) + m16) << 6) + (kh << 5) + (quad << 3));
        bv[i] = *(bf16x8*)(Bs + ((wcol0 + (i << 4) + m16) << 6) + (kh << 5) + (quad << 3));
      }
#pragma unroll
      for (int mi = 0; mi < 4; ++mi)
#pragma unroll
        for (int ni = 0; ni < 4; ++ni)
          acc[mi][ni] = MFMA(av[mi], bv[ni], acc[mi][ni]);
    }
    __syncthreads();
  }

  __bf16 (*Cs)[132] = (__bf16(*)[132])smem;
#pragma unroll
  for (int mi = 0; mi < 4; ++mi)
#pragma unroll
    for (int ni = 0; ni < 4; ++ni) {
      int col = wcol0 + (ni << 4) + m16;
      float bv = bias[tn0 + col];
#pragma unroll
      for (int r = 0; r < 4; ++r)
        Cs[wrow0 + (mi << 4) + (quad << 2) + r][col] =
            tobf((acc[mi][ni][r] + bv) * alpha);
    }
  __syncthreads();
  bf16* O = (z == 0) ? pq : (z == 1) ? pk : v_raw;
  const int crow = t >> 1, ch0 = (t & 1) << 6;   // 2 threads/row, 64 cols each
  long long gb = (long long)(tm0 + crow) * EE + tn0 + ch0;
#pragma unroll
  for (int j = 0; j < 64; j += 8)
    *(uint4*)(O + gb + j) = *(uint4*)&Cs[crow][ch0 + j];
}

// ================= rotary + head-reshape, pure streaming =========================
__global__ __launch_bounds__(256) void rotary_kernel(
    const bf16* __restrict__ pq, const bf16* __restrict__ pk,
    const float* __restrict__ rot_q, const float* __restrict__ rot_k,
    bf16* __restrict__ Qh, bf16* __restrict__ Kh)
{
  const bf16* src = blockIdx.y ? pk : pq;
  const float* rot = blockIdx.y ? rot_k : rot_q;
  bf16* dst = blockIdx.y ? Kh : Qh;
  const int t = threadIdx.x;
  const int row = (blockIdx.x << 2) + (t >> 6);   // l*NB + n
  const int e0 = (t & 63) << 3;                   // 8 elems per lane
  const int l = row >> 3, n = row & 7;
  bf16x8 x = *(const bf16x8*)(src + (long long)row * EE + e0);
  const float* rp = rot + ((((long long)n * LQ + l) * EE + e0) << 1);
  __bf16 vals[8];
#pragma unroll
  for (int j = 0; j < 8; j += 2) {
    float4 cs4 = *(const float4*)(rp + (j << 1));  // c0,s0,c1,s1
    float x0 = bf2f(x[j]);
    float x1 = bf2f(x[j + 1]);
    vals[j]     = tobf(x0 * cs4.x - x1 * cs4.y);
    vals[j + 1] = tobf(x1 * cs4.z + x0 * cs4.w);
  }
  const int h = e0 >> 6, d0 = e0 & 63;
  *(uint4*)(dst + (((long long)(n * NH + h) * LQ + l) * HD + d0)) = *(uint4*)vals;
}

// ================= colsum: 128 K-cols/block, gload_lds Q-dbuf, 1 barrier/iter ====
__global__ __launch_bounds__(256) void colsum_kernel(
    const bf16* __restrict__ Qh, const bf16* __restrict__ Kh,
    float* __restrict__ csum)
{
  __shared__ __align__(16) char QdB[16384];   // [2][64][64] bf16 linear
  __shared__ float cpart[128][2];
  const int bid = blockIdx.y * gridDim.x + blockIdx.x;   // 0..511
  const int xcd = bid & 7, sub = bid >> 3;               // sub in [0,64)
  const int b = (xcd << 3) + (sub >> 3);                 // 0..63
  const int st0 = (sub & 7) << 7;                        // 0..896
  const int t = threadIdx.x;
  const int wave = t >> 6, lane = t & 63;
  const int wm = (wave & 1) << 5, wn = (wave >> 1) << 5;
  const int m16 = lane & 15, quad = lane >> 4;
  const int swz = (m16 & 7) << 4;

  // K fragments (8 x 16B direct global loads, one-time)
  bf16x8 bk[2][2][2];  // [g][ni][kh]
#pragma unroll
  for (int g = 0; g < 2; ++g)
#pragma unroll
    for (int ni = 0; ni < 2; ++ni)
#pragma unroll
      for (int kh = 0; kh < 2; ++kh)
        bk[g][ni][kh] = *(const bf16x8*)(
            Kh + ((long long)b * SK + st0 + (g << 6) + wn + (ni << 4) + m16) * HD
               + (kh << 5) + (quad << 3));

  // staging precompute: 2 chunks of 1KB per wave, source-side swizzle
  int ldsoff[2]; const bf16* qsrc[2];
#pragma unroll
  for (int c = 0; c < 2; ++c) {
    int tb = (wave << 11) + (c << 10) + (lane << 4);
    int row = tb >> 7, cb = tb & 127;
    int srcb = cb ^ ((row & 7) << 4);
    ldsoff[c] = (wave << 11) + (c << 10);
    qsrc[c] = Qh + ((long long)b * LQ + row) * HD + (srcb >> 1);
  }
#pragma unroll
  for (int c = 0; c < 2; ++c) gload_lds16(qsrc[c], QdB + ldsoff[c]);
  __syncthreads();

  const f32x4 zero = {0.f, 0.f, 0.f, 0.f};
  float colp[2][2] = {{0.f, 0.f}, {0.f, 0.f}};
  int cur = 0;
  for (int lt = 0; lt < 16; ++lt) {
    if (lt < 15) {   // async prefetch into other buffer; drained at barrier
#pragma unroll
      for (int c = 0; c < 2; ++c)
        gload_lds16(qsrc[c] + (long long)(lt + 1) * 64 * HD,
                    QdB + ((cur ^ 1) << 13) + ldsoff[c]);
    }
    bf16x8 a0k[2], a1k[2];
#pragma unroll
    for (int kh = 0; kh < 2; ++kh) {
      int byt = ((kh << 6) + (quad << 4)) ^ swz;
      a0k[kh] = *(bf16x8*)(QdB + (cur << 13) + (wm + m16) * 128 + byt);
      a1k[kh] = *(bf16x8*)(QdB + (cur << 13) + (wm + 16 + m16) * 128 + byt);
    }
    f32x4 s[2][2][2];
#pragma unroll
    for (int g = 0; g < 2; ++g)
#pragma unroll
      for (int mi = 0; mi < 2; ++mi)
#pragma unroll
        for (int ni = 0; ni < 2; ++ni) s[g][mi][ni] = zero;
    __builtin_amdgcn_s_setprio(1);
#pragma unroll
    for (int g = 0; g < 2; ++g)
#pragma unroll
      for (int kh = 0; kh < 2; ++kh) {
        s[g][0][0] = MFMA(a0k[kh], bk[g][0][kh], s[g][0][0]);
        s[g][0][1] = MFMA(a0k[kh], bk[g][1][kh], s[g][0][1]);
        s[g][1][0] = MFMA(a1k[kh], bk[g][0][kh], s[g][1][0]);
        s[g][1][1] = MFMA(a1k[kh], bk[g][1][kh], s[g][1][1]);
      }
    __builtin_amdgcn_s_setprio(0);
#pragma unroll
    for (int g = 0; g < 2; ++g)
#pragma unroll
      for (int mi = 0; mi < 2; ++mi)
#pragma unroll
        for (int ni = 0; ni < 2; ++ni)
#pragma unroll
          for (int r = 0; r < 4; ++r)
            colp[g][ni] += exp2f(s[g][mi][ni][r]);
    __syncthreads();          // the ONLY barrier (also drains prefetch)
    cur ^= 1;
  }
#pragma unroll
  for (int g = 0; g < 2; ++g)
#pragma unroll
    for (int ni = 0; ni < 2; ++ni) {
      float v = colp[g][ni];
      v += __shfl_down(v, 32, 64);
      v += __shfl_down(v, 16, 64);
      if (quad == 0) cpart[(g << 6) + wn + (ni << 4) + m16][wm >> 5] = v;
    }
  __syncthreads();
  if (t < 128) csum[b * SK + st0 + t] = cpart[t][0] + cpart[t][1];
}

// ================= fused flash: mem + main + gate combine, K/V double-buffer =====
// (round-6 proven structure: reg-staged K/V dbuf, 2 barriers/iter, cross-wave P
// with packed 8B writes + XOR swizzle; exp -> native exp2 via pre-scaled Q)
__global__ __launch_bounds__(256) void attn_fused(
    const bf16* __restrict__ Qh, const bf16* __restrict__ Kh,
    const bf16* __restrict__ Vt, const bf16* __restrict__ km,
    const bf16* __restrict__ vmt, const float* __restrict__ csum,
    const float* __restrict__ Vsum, const int* __restrict__ mask,
    const float* __restrict__ gate, bf16* __restrict__ comb)
{
  __shared__ __align__(16) __bf16 Kd[2][64][72];
  __shared__ __align__(16) __bf16 Vd[2][64][72];
  __shared__ __align__(16) __bf16 Ps[4096];   // [64][64] swizzled
  __shared__ __align__(16) float rcs[SK];
  __shared__ __align__(16) float mskf[MMEM];
  const int bid = blockIdx.y * gridDim.x + blockIdx.x;   // 0..1023
  const int xcd = bid & 7, sub = bid >> 3;               // sub in [0,128)
  const int b = (xcd << 3) + (sub >> 4);                 // 0..63
  const int tm0 = (sub & 15) << 6;
  const int n = b >> 3, h = b & 7;
  const int t = threadIdx.x;
  const int lrow = t >> 2, lcol = (t & 3) << 4;
  const int wave = t >> 6, lane = t & 63;
  const int wm = (wave & 1) << 5, wn = (wave >> 1) << 5;
  const int m16 = lane & 15, quad = lane >> 4;
  const int swz = (m16 & 7) << 4;
  __shared__ float rpa[64][2];
  __shared__ float rpm[64][2];

#pragma unroll
  for (int i = 0; i < 4; ++i)
    rcs[t + i * 256] = 1.f / csum[b * SK + t + i * 256];
  mskf[t] = mask[n * MMEM + t] ? 0.f : 1.f;
  {
    const bf16* qp = Qh + ((long long)b * LQ + tm0 + lrow) * HD + lcol;
    *(bf16x8*)&Kd[0][lrow][lcol] = *(const bf16x8*)qp;
    *(bf16x8*)&Kd[0][lrow][lcol + 8] = *(const bf16x8*)(qp + 8);
  }
  __syncthreads();
  bf16x8 aq[2][2];
#pragma unroll
  for (int li = 0; li < 2; ++li)
#pragma unroll
    for (int kh = 0; kh < 2; ++kh)
      aq[li][kh] = *(bf16x8*)&Kd[0][wm + (li << 4) + m16][(kh << 5) + (quad << 3)];

  const bf16* kbase_m = km + ((long long)b * MMEM + lrow) * HD + lcol;
  const bf16* vbase_m = vmt + ((long long)b * HD + lrow) * MMEM + lcol;
  // stage mem tile 0 into buf1 (Kd[0] still being read above -> different buf)
  {
    bf16x8 k0 = *(const bf16x8*)kbase_m;
    bf16x8 k1 = *(const bf16x8*)(kbase_m + 8);
    bf16x8 v0 = *(const bf16x8*)vbase_m;
    bf16x8 v1 = *(const bf16x8*)(vbase_m + 8);
    *(bf16x8*)&Kd[1][lrow][lcol] = k0;
    *(bf16x8*)&Kd[1][lrow][lcol + 8] = k1;
    *(bf16x8*)&Vd[1][lrow][lcol] = v0;
    *(bf16x8*)&Vd[1][lrow][lcol + 8] = v1;
  }
  __syncthreads();

  const f32x4 zero = {0.f, 0.f, 0.f, 0.f};
  // ---------------- mem branch (4 tiles of km/vmt) ----------------
  f32x4 m00 = zero, m01 = zero, m10 = zero, m11 = zero;
  float rsm[2] = {0.f, 0.f};
  int cur = 1;
  for (int mt = 0; mt < 4; ++mt) {
    bf16x8 kr0, kr1, vr0, vr1;
    if (mt < 3) {
      const bf16* kp = kbase_m + (long long)((mt + 1) << 6) * HD;
      const bf16* vp = vbase_m + ((mt + 1) << 6);
      kr0 = *(const bf16x8*)kp;
      kr1 = *(const bf16x8*)(kp + 8);
      vr0 = *(const bf16x8*)vp;
      vr1 = *(const bf16x8*)(vp + 8);
    }
    f32x4 s00 = zero, s01 = zero, s10 = zero, s11 = zero;
    __builtin_amdgcn_s_setprio(1);
#pragma unroll
    for (int kh = 0; kh < 2; ++kh) {
      bf16x8 ak0 = *(bf16x8*)&Kd[cur][wn + m16][(kh << 5) + (quad << 3)];
      bf16x8 ak1 = *(bf16x8*)&Kd[cur][wn + 16 + m16][(kh << 5) + (quad << 3)];
      s00 = MFMA(ak0, aq[0][kh], s00);
      s01 = MFMA(ak0, aq[1][kh], s01);
      s10 = MFMA(ak1, aq[0][kh], s10);
      s11 = MFMA(ak1, aq[1][kh], s11);
    }
    __builtin_amdgcn_s_setprio(0);
    {
      char* pA = (char*)Ps + (wm + m16) * 128;
      char* pB = (char*)Ps + (wm + 16 + m16) * 128;
#pragma unroll
      for (int si = 0; si < 2; ++si) {
        int sloc = wn + (si << 4) + (quad << 2);
        f32x4 mf4 = *(const f32x4*)&mskf[(mt << 6) + sloc];
        f32x4 sA = si ? s10 : s00;
        f32x4 sB = si ? s11 : s01;
        __bf16 vA[4], vB[4];
#pragma unroll
        for (int r = 0; r < 4; ++r) {
          float pa = exp2f(sA[r]) * mf4[r];
          rsm[0] += pa; vA[r] = tobf(pa);
          float pb = exp2f(sB[r]) * mf4[r];
          rsm[1] += pb; vB[r] = tobf(pb);
        }
        int sbyte = (sloc << 1) ^ swz;
        *(uint2*)(pA + sbyte) = *(uint2*)vA;
        *(uint2*)(pB + sbyte) = *(uint2*)vB;
      }
    }
    __syncthreads();   // B2: P visible; all reads of Kd[cur] (QK) done
    if (mt < 3) {      // stage next tile into the idle buffer
      *(bf16x8*)&Kd[cur ^ 1][lrow][lcol] = kr0;
      *(bf16x8*)&Kd[cur ^ 1][lrow][lcol + 8] = kr1;
      *(bf16x8*)&Vd[cur ^ 1][lrow][lcol] = vr0;
      *(bf16x8*)&Vd[cur ^ 1][lrow][lcol + 8] = vr1;
    }
    __builtin_amdgcn_s_setprio(1);
#pragma unroll
    for (int kh = 0; kh < 2; ++kh) {
      int sb = (kh << 6) + (quad << 4);
      bf16x8 ap0 = *(bf16x8*)((char*)Ps + (wm + m16) * 128 + (sb ^ swz));
      bf16x8 ap1 = *(bf16x8*)((char*)Ps + (wm + 16 + m16) * 128 + (sb ^ swz));
      bf16x8 bv0 = *(bf16x8*)&Vd[cur][wn + m16][(kh << 5) + (quad << 3)];
      bf16x8 bv1 = *(bf16x8*)&Vd[cur][wn + 16 + m16][(kh << 5) + (quad << 3)];
      m00 = MFMA(ap0, bv0, m00);
      m01 = MFMA(ap0, bv1, m01);
      m10 = MFMA(ap1, bv0, m10);
      m11 = MFMA(ap1, bv1, m11);
    }
    __builtin_amdgcn_s_setprio(0);
    __syncthreads();   // B3: PV done; staged tile + Ps safe for next iter
    cur ^= 1;
  }

  // ---------------- main branch (16 tiles of Kh/Vt) ----------------
  f32x4 o00 = zero, o01 = zero, o10 = zero, o11 = zero;
  float rsa[2] = {0.f, 0.f};
  const bf16* kbase = Kh + ((long long)b * SK + lrow) * HD + lcol;
  const bf16* vbase = Vt + ((long long)b * HD + lrow) * SK + lcol;
  {  // stage main tile 0 into buf1 (last mem iter read buf0; buf1 idle)
    bf16x8 k0 = *(const bf16x8*)kbase;
    bf16x8 k1 = *(const bf16x8*)(kbase + 8);
    bf16x8 v0 = *(const bf16x8*)vbase;
    bf16x8 v1 = *(const bf16x8*)(vbase + 8);
    *(bf16x8*)&Kd[1][lrow][lcol] = k0;
    *(bf16x8*)&Kd[1][lrow][lcol + 8] = k1;
    *(bf16x8*)&Vd[1][lrow][lcol] = v0;
    *(bf16x8*)&Vd[1][lrow][lcol + 8] = v1;
  }
  __syncthreads();
  cur = 1;
  for (int st = 0; st < 16; ++st) {
    bf16x8 kr0, kr1, vr0, vr1;
    if (st < 15) {
      const bf16* kp = kbase + (long long)((st + 1) << 6) * HD;
      const bf16* vp = vbase + ((st + 1) << 6);
      kr0 = *(const bf16x8*)kp;
      kr1 = *(const bf16x8*)(kp + 8);
      vr0 = *(const bf16x8*)vp;
      vr1 = *(const bf16x8*)(vp + 8);
    }
    f32x4 s00 = zero, s01 = zero, s10 = zero, s11 = zero;
    __builtin_amdgcn_s_setprio(1);
#pragma unroll
    for (int kh = 0; kh < 2; ++kh) {
      bf16x8 ak0 = *(bf16x8*)&Kd[cur][wn + m16][(kh << 5) + (quad << 3)];
      bf16x8 ak1 = *(bf16x8*)&Kd[cur][wn + 16 + m16][(kh << 5) + (quad << 3)];
      s00 = MFMA(ak0, aq[0][kh], s00);
      s01 = MFMA(ak0, aq[1][kh], s01);
      s10 = MFMA(ak1, aq[0][kh], s10);
      s11 = MFMA(ak1, aq[1][kh], s11);
    }
    __builtin_amdgcn_s_setprio(0);
    {
      char* pA = (char*)Ps + (wm + m16) * 128;
      char* pB = (char*)Ps + (wm + 16 + m16) * 128;
#pragma unroll
      for (int si = 0; si < 2; ++si) {
        int sloc = wn + (si << 4) + (quad << 2);
        f32x4 rc4 = *(const f32x4*)&rcs[(st << 6) + sloc];
        f32x4 sA = si ? s10 : s00;
        f32x4 sB = si ? s11 : s01;
        __bf16 vA[4], vB[4];
#pragma unroll
        for (int r = 0; r < 4; ++r) {
          float pa = exp2f(sA[r]) * rc4[r];
          rsa[0] += pa; vA[r] = tobf(pa);
          float pb = exp2f(sB[r]) * rc4[r];
          rsa[1] += pb; vB[r] = tobf(pb);
        }
        int sbyte = (sloc << 1) ^ swz;
        *(uint2*)(pA + sbyte) = *(uint2*)vA;
        *(uint2*)(pB + sbyte) = *(uint2*)vB;
      }
    }
    __syncthreads();   // B2
    if (st < 15) {
      *(bf16x8*)&Kd[cur ^ 1][lrow][lcol] = kr0;
      *(bf16x8*)&Kd[cur ^ 1][lrow][lcol + 8] = kr1;
      *(bf16x8*)&Vd[cur ^ 1][lrow][lcol] = vr0;
      *(bf16x8*)&Vd[cur ^ 1][lrow][lcol + 8] = vr1;
    }
    __builtin_amdgcn_s_setprio(1);
#pragma unroll
    for (int kh = 0; kh < 2; ++kh) {
      int sb = (kh << 6) + (quad << 4);
      bf16x8 ap0 = *(bf16x8*)((char*)Ps + (wm + m16) * 128 + (sb ^ swz));
      bf16x8 ap1 = *(bf16x8*)((char*)Ps + (wm + 16 + m16) * 128 + (sb ^ swz));
      bf16x8 bv0 = *(bf16x8*)&Vd[cur][wn + m16][(kh << 5) + (quad << 3)];
      bf16x8 bv1 = *(bf16x8*)&Vd[cur][wn + 16 + m16][(kh << 5) + (quad << 3)];
      o00 = MFMA(ap0, bv0, o00);
      o01 = MFMA(ap0, bv1, o01);
      o10 = MFMA(ap1, bv0, o10);
      o11 = MFMA(ap1, bv1, o11);
    }
    __builtin_amdgcn_s_setprio(0);
    __syncthreads();   // B3
    cur ^= 1;
  }

  // ---------------- reductions (both branches) ----------------
#pragma unroll
  for (int li = 0; li < 2; ++li) {
    float va = rsa[li];
    va += __shfl_xor(va, 16, 64);
    va += __shfl_xor(va, 32, 64);
    float vm = rsm[li];
    vm += __shfl_xor(vm, 16, 64);
    vm += __shfl_xor(vm, 32, 64);
    if (quad == 0) {
      rpa[wm + (li << 4) + m16][wn >> 5] = va;
      rpm[wm + (li << 4) + m16][wn >> 5] = vm;
    }
  }
  __syncthreads();

  // ---------------- gate combine in f32, single bf16 write ----------------
  const float* vs = Vsum + b * HD;
  const float g = 1.f / (1.f + __expf(-gate[h]));
  f32x4 oacc[2][2] = {{o00, o01}, {o10, o11}};
  f32x4 macc[2][2] = {{m00, m01}, {m10, m11}};
  for (int mi = 0; mi < 2; ++mi)
    for (int ni = 0; ni < 2; ++ni) {
      int col = wn + (ni << 4) + m16;
      float vsc = 1e-8f * vs[col];
      for (int r = 0; r < 4; ++r) {
        int row = wm + (mi << 4) + (quad << 2) + r;
        float ra = rpa[row][0] + rpa[row][1];
        float rm = rpm[row][0] + rpm[row][1];
        float oa = (oacc[mi][ni][r] + vsc) / (ra + (float)SK * 1e-8f);
        float om = macc[mi][ni][r] / rm;
        Kd[0][row][col] = tobf(g * om + (1.f - g) * oa);
      }
    }
  __syncthreads();
  uint4 u0 = *(uint4*)&Kd[0][lrow][lcol];
  uint4 u1 = *(uint4*)&Kd[0][lrow][lcol + 8];
  long long gb = ((long long)b * LQ + tm0 + lrow) * HD + lcol;
  *(uint4*)(comb + gb) = u0;
  *(uint4*)(comb + gb + 8) = u1;
}

// ================= out proj, m97-structure (A = fused comb buffer) ===============
__global__ __launch_bounds__(256) void gemm_out(
    const bf16* __restrict__ comb, const bf16* __restrict__ opwb,
    const float* __restrict__ opb, float* __restrict__ out)
{
  __shared__ __align__(16) char smem[32768];
  __bf16* As = (__bf16*)smem;             // [128][64] linear
  __bf16* Bs = (__bf16*)(smem + 16384);   // [128][64] linear
  const int bid2 = blockIdx.y * gridDim.x + blockIdx.x;  // 0..255
  const int xcd = bid2 & 7, sub = bid2 >> 3;             // sub in [0,32)
  const int by = (xcd << 3) + (sub >> 2);                // 0..63
  const int bx = sub & 3;                                // 0..3
  const int tm0 = by << 7, tn0 = bx << 7;
  const int t = threadIdx.x;
  const int wave = t >> 6, lane = t & 63;
  const int wrow0 = (wave & 1) << 6, wcol0 = (wave >> 1) << 6;
  const int m16 = lane & 15, quad = lane >> 4;

  const f32x4 zero = {0.f, 0.f, 0.f, 0.f};
  f32x4 acc[4][4];
#pragma unroll
  for (int mi = 0; mi < 4; ++mi)
#pragma unroll
    for (int ni = 0; ni < 4; ++ni) acc[mi][ni] = zero;

  const bf16* Bb = opwb + (long long)tn0 * EE;
  const int ob_u = wave << 10;

  for (int k0 = 0; k0 < EE; k0 += 64) {
    const int h = k0 >> 6;
#pragma unroll
    for (int c = 0; c < 4; ++c) {
      int ob = (c << 12) + ob_u;
      int obl = ob + (lane << 4);
      int row = obl >> 7;
      int ce = (obl & 127) >> 1;
      int arow = tm0 + row;
      int l = arow >> 3, nn = arow & 7;
      gload_lds16(comb + (((long long)(nn * NH + h) * LQ + l) * HD + ce),
                  smem + ob);
      gload_lds16(Bb + (long long)row * EE + k0 + ce, smem + 16384 + ob);
    }
    __syncthreads();
#pragma unroll
    for (int kh = 0; kh < 2; ++kh) {
      bf16x8 av[4], bv[4];
#pragma unroll
      for (int i = 0; i < 4; ++i) {
        av[i] = *(bf16x8*)(As + ((wrow0 + (i << 4) + m16) << 6) + (kh << 5) + (quad << 3));
        bv[i] = *(bf16x8*)(Bs + ((wcol0 + (i << 4) + m16) << 6) + (kh << 5) + (quad << 3));
      }
#pragma unroll
      for (int mi = 0; mi < 4; ++mi)
#pragma unroll
        for (int ni = 0; ni < 4; ++ni)
          acc[mi][ni] = MFMA(av[mi], bv[ni], acc[mi][ni]);
    }
    __syncthreads();
  }

#pragma unroll
  for (int mi = 0; mi < 4; ++mi)
#pragma unroll
    for (int ni = 0; ni < 4; ++ni) {
      int col = tn0 + wcol0 + (ni << 4) + m16;
      float bv = opb[col];
      int row0 = tm0 + wrow0 + (mi << 4) + (quad << 2);
#pragma unroll
      for (int r = 0; r < 4; ++r)
        out[(long long)(row0 + r) * EE + col] = acc[mi][ni][r] + bv;
    }
}

// ================= LDS-tiled transposes (no 2B-granular scatter) =================
__global__ __launch_bounds__(256) void v_transpose(
    const bf16* __restrict__ raw, bf16* __restrict__ Vt,
    float* __restrict__ Vsum)
{
  __shared__ __align__(16) __bf16 Ts[64][72];
  const int bh = blockIdx.y;             // n*NH + h
  const int n = bh >> 3, h = bh & 7;
  const int s0 = blockIdx.x << 6;
  const int t = threadIdx.x;
  const int i = t >> 2, c0 = (t & 3) << 4;
  const bf16* rp = raw + ((long long)(s0 + i) * NB + n) * EE + h * HD + c0;
  *(bf16x8*)&Ts[i][c0] = *(const bf16x8*)rp;
  *(bf16x8*)&Ts[i][c0 + 8] = *(const bf16x8*)(rp + 8);
  __syncthreads();
  const int d = t >> 2, j0 = (t & 3) << 4;
  __bf16 vals[16];
  float part = 0.f;
#pragma unroll
  for (int j = 0; j < 16; ++j) { vals[j] = Ts[j0 + j][d]; part += bf2f(vals[j]); }
  bf16* wp = Vt + ((long long)bh * HD + d) * SK + s0 + j0;
  *(uint4*)wp = *(uint4*)&vals[0];
  *(uint4*)(wp + 8) = *(uint4*)&vals[8];
  part += __shfl_xor(part, 1, 64);
  part += __shfl_xor(part, 2, 64);
  if ((t & 3) == 0) atomicAdd(&Vsum[bh * HD + d], part);
}

__global__ __launch_bounds__(256) void mem_prep(
    const float* __restrict__ k_mem, const float* __restrict__ v_mem,
    bf16* __restrict__ km, bf16* __restrict__ vmt)
{
  __shared__ __align__(16) __bf16 Ts[64][72];
  const int bh = blockIdx.y;             // n*NH + h
  const int n = bh >> 3, h = bh & 7;
  const int m0 = blockIdx.x << 6;
  const int t = threadIdx.x;
  const int i = t >> 2, c0 = (t & 3) << 4;
  const float* kp = k_mem + ((long long)(m0 + i) * NB + n) * EE + h * HD + c0;
  const float* vp = v_mem + ((long long)(m0 + i) * NB + n) * EE + h * HD + c0;
  bf16x8 kv0 = load8(kp), kv1 = load8(kp + 8);
  bf16x8 vv0 = load8(vp), vv1 = load8(vp + 8);
  bf16* kw = km + ((long long)bh * MMEM + m0 + i) * HD + c0;
  *(bf16x8*)kw = kv0;
  *(bf16x8*)(kw + 8) = kv1;
  *(bf16x8*)&Ts[i][c0] = vv0;
  *(bf16x8*)&Ts[i][c0 + 8] = vv1;
  __syncthreads();
  const int d = t >> 2, j0 = (t & 3) << 4;
  __bf16 vals[16];
#pragma unroll
  for (int j = 0; j < 16; ++j) vals[j] = Ts[j0 + j][d];
  bf16* wp = vmt + ((long long)bh * HD + d) * MMEM + m0 + j0;
  *(uint4*)wp = *(uint4*)&vals[0];
  *(uint4*)(wp + 8) = *(uint4*)&vals[8];
}

extern "C" void kernel_launch(void* const* d_in, const int* in_sizes, int n_in,
                              void* d_out, int out_size, void* d_ws, size_t ws_size,
                              hipStream_t stream) {
  const float* query = (const float*)d_in[0];
  const float* key   = (const float*)d_in[1];
  const float* value = (const float*)d_in[2];
  const float* ipw   = (const float*)d_in[3];
  const float* ipb   = (const float*)d_in[4];
  const float* opw   = (const float*)d_in[5];
  const float* opb   = (const float*)d_in[6];
  const float* rot_q = (const float*)d_in[7];
  const float* rot_k = (const float*)d_in[8];
  const float* k_mem = (const float*)d_in[9];
  const float* v_mem = (const float*)d_in[10];
  const float* gate  = (const float*)d_in[11];
  const int*  mask   = (const int*)d_in[12];
  float* out = (float*)d_out;

  char* w = (char*)d_ws;
  size_t off = 0;
  auto carve = [&](size_t bytes) -> char* {
    char* p = w + off;
    off += (bytes + 255) & ~(size_t)255;
    return p;
  };
  bf16* qc    = (bf16*)carve((size_t)LQ * NB * EE * 2);
  bf16* kc    = (bf16*)carve((size_t)SK * NB * EE * 2);
  bf16* vc    = (bf16*)carve((size_t)SK * NB * EE * 2);
  bf16* ipwb  = (bf16*)carve((size_t)3 * EE * EE * 2);
  bf16* opwb  = (bf16*)carve((size_t)EE * EE * 2);
  bf16* v_raw = (bf16*)carve((size_t)SK * NB * EE * 2);
  bf16* Qh    = (bf16*)carve((size_t)NBH * LQ * HD * 2);
  bf16* Kh    = (bf16*)carve((size_t)NBH * SK * HD * 2);
  bf16* Vt    = (bf16*)carve((size_t)NBH * HD * SK * 2);
  bf16* km    = (bf16*)carve((size_t)NBH * MMEM * HD * 2);
  bf16* vmt   = (bf16*)carve((size_t)NBH * HD * MMEM * 2);
  float* csum = (float*)carve((size_t)NBH * SK * 4);
  float* Vsum = (float*)carve((size_t)NBH * HD * 4);
  bf16* comb  = (bf16*)carve((size_t)NBH * LQ * HD * 2);
  bf16* pkbuf = (bf16*)carve((size_t)NBH * LQ * HD * 2);
  if (off > ws_size) {
    hipMemsetAsync(d_out, 0, (size_t)out_size * 4, stream);
    return;
  }
  // pq aliases comb: comb is only written by attn_fused, well after rotary
  // consumed pq. pkbuf is rotary's K staging.
  bf16* pq = comb;
  bf16* pk = pkbuf;

  // 0) pre-convert GEMM inputs to bf16; zero Vsum accumulators
  convert5<<<(3 * CVT_T0 + CVT_T3 + CVT_T4) / 256, 256, 0, stream>>>(
      query, key, value, ipw, opw, qc, kc, vc, ipwb, opwb);
  hipMemsetAsync(Vsum, 0, (size_t)NBH * HD * 4, stream);

  // 1) q/k/v projections (q alpha folds log2e for exp2 softmax downstream)
  gemm_proj3<<<dim3(EE / 128, (LQ * NB) / 128, 3), 256, 0, stream>>>(
      qc, kc, vc, ipwb, ipb, pq, pk, v_raw);

  // 1b) rotary + head reshape as a pure streaming kernel
  rotary_kernel<<<dim3((LQ * NB) / 4, 2), 256, 0, stream>>>(
      pq, pk, rot_q, rot_k, Qh, Kh);

  // 2) v transpose (LDS-tiled, fused Vsum atomics); mem k/v repack
  v_transpose<<<dim3(SK / 64, NBH), 256, 0, stream>>>(v_raw, Vt, Vsum);
  mem_prep<<<dim3(MMEM / 64, NBH), 256, 0, stream>>>(k_mem, v_mem, km, vmt);

  // 3) column sums (128 cols/block, gload_lds Q-dbuf, 1 barrier/iter, exp2)
  colsum_kernel<<<dim3(SK / 128, NBH), 256, 0, stream>>>(Qh, Kh, csum);

  // 4) fused flash (round-6 structure: K/V reg-dbuf, 2 barriers/iter, exp2)
  attn_fused<<<dim3(LQ / 64, NBH), 256, 0, stream>>>(
      Qh, Kh, Vt, km, vmt, csum, Vsum, mask, gate, comb);

  // 5) out-proj, m97 structure, single A buffer
  gemm_out<<<dim3(4, 64), 256, 0, stream>>>(comb, opwb, opb, out);
}

// Round 11
// 299.611 us; speedup vs baseline: 1.1465x; 1.1465x over previous
//
#include <hip/hip_runtime.h>
#include <hip/hip_bf16.h>

typedef __hip_bfloat16 bf16;
typedef __bf16 bf16x8 __attribute__((ext_vector_type(8)));
typedef float f32x4 __attribute__((ext_vector_type(4)));

#define LQ 1024
#define SK 1024
#define MMEM 256
#define NB 8
#define EE 512
#define NH 8
#define HD 64
#define NBH 64  // NB*NH batched (n,h) pairs

__device__ inline __bf16 tobf(float f) {
  __hip_bfloat16 h = __float2bfloat16(f);
  return *reinterpret_cast<__bf16*>(&h);
}
__device__ inline float bf2f(__bf16 x) {
  unsigned short u; __builtin_memcpy(&u, &x, 2);
  unsigned int v = (unsigned int)u << 16;
  float f; __builtin_memcpy(&f, &v, 4);
  return f;
}
__device__ inline f32x4 MFMA(bf16x8 a, bf16x8 b, f32x4 c) {
  return __builtin_amdgcn_mfma_f32_16x16x32_bf16(a, b, c, 0, 0, 0);
}
// native 2^x (single v_exp_f32, no libm fixup code -- exp2f pulls in the
// correctly-rounded OCML path which cost +16 VGPR and an occupancy tier)
__device__ inline float exp2n(float x) { return __builtin_amdgcn_exp2f(x); }

// async global->LDS, 16B per lane. LDS dest is wave-uniform base + lane*16.
__device__ inline void gload_lds16(const bf16* g, void* l) {
  __builtin_amdgcn_global_load_lds(
      (const __attribute__((address_space(1))) void*)g,
      (__attribute__((address_space(3))) void*)l, 16, 0, 0);
}

__device__ inline bf16x8 load8(const float* p) {
  float4 a = *(const float4*)p;
  float4 b = *(const float4*)(p + 4);
  bf16x8 r;
  r[0] = tobf(a.x); r[1] = tobf(a.y); r[2] = tobf(a.z); r[3] = tobf(a.w);
  r[4] = tobf(b.x); r[5] = tobf(b.y); r[6] = tobf(b.z); r[7] = tobf(b.w);
  return r;
}

// ================= bf16 pre-conversion of GEMM inputs ============================
#define CVT_T0 524288   // threads per q/k/v region (8 elems each)
#define CVT_T3 98304    // ipw
#define CVT_T4 32768    // opw
__global__ __launch_bounds__(256) void convert5(
    const float* __restrict__ q, const float* __restrict__ k,
    const float* __restrict__ v, const float* __restrict__ w,
    const float* __restrict__ o, bf16* __restrict__ qc, bf16* __restrict__ kc,
    bf16* __restrict__ vc, bf16* __restrict__ wc, bf16* __restrict__ oc)
{
  long long t = (long long)blockIdx.x * 256 + threadIdx.x;
  const float* src; bf16* dst; long long idx;
  if (t < CVT_T0)               { src = q; dst = qc; idx = t; }
  else if (t < 2 * CVT_T0)      { src = k; dst = kc; idx = t - CVT_T0; }
  else if (t < 3 * CVT_T0)      { src = v; dst = vc; idx = t - 2 * CVT_T0; }
  else if (t < 3 * CVT_T0 + CVT_T3) { src = w; dst = wc; idx = t - 3 * CVT_T0; }
  else                          { src = o; dst = oc; idx = t - 3 * CVT_T0 - CVT_T3; }
  *(bf16x8*)(dst + idx * 8) = load8(src + idx * 8);
}

// ================= 3-in-1 projection GEMM, m97-structure, PURE GEMM ==============
// z=0 alpha folds log2e so downstream softmax uses native exp2 (saves one v_mul
// per exp in colsum + attn, all mathematically identical: exp(S)=2^(S*log2e)).
__global__ __launch_bounds__(256) void gemm_proj3(
    const bf16* __restrict__ qc, const bf16* __restrict__ kc,
    const bf16* __restrict__ vc, const bf16* __restrict__ ipwb,
    const float* __restrict__ ipb, bf16* __restrict__ pq,
    bf16* __restrict__ pk, bf16* __restrict__ v_raw)
{
  __shared__ __align__(16) char smem[33792];
  __bf16* As = (__bf16*)smem;             // [128][64] linear, 16384 B
  __bf16* Bs = (__bf16*)(smem + 16384);   // [128][64] linear, 16384 B
  const int z = blockIdx.z;
  const bf16* A = (z == 0) ? qc : (z == 1) ? kc : vc;
  const bf16* W = ipwb + (long long)z * EE * EE;
  const float* bias = ipb + z * EE;
  const float alpha = (z == 0) ? 0.1803368801f : 1.f;  // 0.125 * log2(e)
  const int bid2 = blockIdx.y * gridDim.x + blockIdx.x;
  const int xcd = bid2 & 7, sub = bid2 >> 3;       // sub in [0,32)
  const int by = (xcd << 3) + (sub >> 2);          // 0..63
  const int bx = sub & 3;                          // 0..3
  const int tm0 = by << 7, tn0 = bx << 7;          // 128 x 128
  const int t = threadIdx.x;
  const int wave = t >> 6, lane = t & 63;
  const int wrow0 = (wave & 1) << 6, wcol0 = (wave >> 1) << 6;
  const int m16 = lane & 15, quad = lane >> 4;

  const f32x4 zero = {0.f, 0.f, 0.f, 0.f};
  f32x4 acc[4][4];
#pragma unroll
  for (int mi = 0; mi < 4; ++mi)
#pragma unroll
    for (int ni = 0; ni < 4; ++ni) acc[mi][ni] = zero;

  const bf16* Ab = A + (long long)tm0 * EE;
  const bf16* Bb = W + (long long)tn0 * EE;
  const int ob_u = wave << 10;  // wave-uniform byte base within 4KB chunk

  for (int k0 = 0; k0 < EE; k0 += 64) {
#pragma unroll
    for (int c = 0; c < 4; ++c) {
      int ob = (c << 12) + ob_u;          // uniform LDS byte base
      int obl = ob + (lane << 4);         // this lane's slot
      int row = obl >> 7;                 // tile row (stride 128 B)
      int ce = (obl & 127) >> 1;          // element within row
      gload_lds16(Ab + (long long)row * EE + k0 + ce, smem + ob);
      gload_lds16(Bb + (long long)row * EE + k0 + ce, smem + 16384 + ob);
    }
    __syncthreads();
#pragma unroll
    for (int kh = 0; kh < 2; ++kh) {
      bf16x8 av[4], bv[4];
#pragma unroll
      for (int i = 0; i < 4; ++i) {
        av[i] = *(bf16x8*)(As + ((wrow0 + (i << 4) + m16) << 6) + (kh << 5) + (quad << 3));
        bv[i] = *(bf16x8*)(Bs + ((wcol0 + (i << 4) + m16) << 6) + (kh << 5) + (quad << 3));
      }
#pragma unroll
      for (int mi = 0; mi < 4; ++mi)
#pragma unroll
        for (int ni = 0; ni < 4; ++ni)
          acc[mi][ni] = MFMA(av[mi], bv[ni], acc[mi][ni]);
    }
    __syncthreads();
  }

  __bf16 (*Cs)[132] = (__bf16(*)[132])smem;
#pragma unroll
  for (int mi = 0; mi < 4; ++mi)
#pragma unroll
    for (int ni = 0; ni < 4; ++ni) {
      int col = wcol0 + (ni << 4) + m16;
      float bv = bias[tn0 + col];
#pragma unroll
      for (int r = 0; r < 4; ++r)
        Cs[wrow0 + (mi << 4) + (quad << 2) + r][col] =
            tobf((acc[mi][ni][r] + bv) * alpha);
    }
  __syncthreads();
  bf16* O = (z == 0) ? pq : (z == 1) ? pk : v_raw;
  const int crow = t >> 1, ch0 = (t & 1) << 6;   // 2 threads/row, 64 cols each
  long long gb = (long long)(tm0 + crow) * EE + tn0 + ch0;
#pragma unroll
  for (int j = 0; j < 64; j += 8)
    *(uint4*)(O + gb + j) = *(uint4*)&Cs[crow][ch0 + j];
}

// ================= rotary + head-reshape, pure streaming =========================
__global__ __launch_bounds__(256) void rotary_kernel(
    const bf16* __restrict__ pq, const bf16* __restrict__ pk,
    const float* __restrict__ rot_q, const float* __restrict__ rot_k,
    bf16* __restrict__ Qh, bf16* __restrict__ Kh)
{
  const bf16* src = blockIdx.y ? pk : pq;
  const float* rot = blockIdx.y ? rot_k : rot_q;
  bf16* dst = blockIdx.y ? Kh : Qh;
  const int t = threadIdx.x;
  const int row = (blockIdx.x << 2) + (t >> 6);   // l*NB + n
  const int e0 = (t & 63) << 3;                   // 8 elems per lane
  const int l = row >> 3, n = row & 7;
  bf16x8 x = *(const bf16x8*)(src + (long long)row * EE + e0);
  const float* rp = rot + ((((long long)n * LQ + l) * EE + e0) << 1);
  __bf16 vals[8];
#pragma unroll
  for (int j = 0; j < 8; j += 2) {
    float4 cs4 = *(const float4*)(rp + (j << 1));  // c0,s0,c1,s1
    float x0 = bf2f(x[j]);
    float x1 = bf2f(x[j + 1]);
    vals[j]     = tobf(x0 * cs4.x - x1 * cs4.y);
    vals[j + 1] = tobf(x1 * cs4.z + x0 * cs4.w);
  }
  const int h = e0 >> 6, d0 = e0 & 63;
  *(uint4*)(dst + (((long long)(n * NH + h) * LQ + l) * HD + d0)) = *(uint4*)vals;
}

// ================= colsum: 128 K-cols/block, gload_lds Q-dbuf, 1 barrier/iter ====
__global__ __launch_bounds__(256) void colsum_kernel(
    const bf16* __restrict__ Qh, const bf16* __restrict__ Kh,
    float* __restrict__ csum)
{
  __shared__ __align__(16) char QdB[16384];   // [2][64][64] bf16 linear
  __shared__ float cpart[128][2];
  const int bid = blockIdx.y * gridDim.x + blockIdx.x;   // 0..511
  const int xcd = bid & 7, sub = bid >> 3;               // sub in [0,64)
  const int b = (xcd << 3) + (sub >> 3);                 // 0..63
  const int st0 = (sub & 7) << 7;                        // 0..896
  const int t = threadIdx.x;
  const int wave = t >> 6, lane = t & 63;
  const int wm = (wave & 1) << 5, wn = (wave >> 1) << 5;
  const int m16 = lane & 15, quad = lane >> 4;
  const int swz = (m16 & 7) << 4;

  // K fragments (8 x 16B direct global loads, one-time)
  bf16x8 bk[2][2][2];  // [g][ni][kh]
#pragma unroll
  for (int g = 0; g < 2; ++g)
#pragma unroll
    for (int ni = 0; ni < 2; ++ni)
#pragma unroll
      for (int kh = 0; kh < 2; ++kh)
        bk[g][ni][kh] = *(const bf16x8*)(
            Kh + ((long long)b * SK + st0 + (g << 6) + wn + (ni << 4) + m16) * HD
               + (kh << 5) + (quad << 3));

  // staging precompute: 2 chunks of 1KB per wave, source-side swizzle
  int ldsoff[2]; const bf16* qsrc[2];
#pragma unroll
  for (int c = 0; c < 2; ++c) {
    int tb = (wave << 11) + (c << 10) + (lane << 4);
    int row = tb >> 7, cb = tb & 127;
    int srcb = cb ^ ((row & 7) << 4);
    ldsoff[c] = (wave << 11) + (c << 10);
    qsrc[c] = Qh + ((long long)b * LQ + row) * HD + (srcb >> 1);
  }
#pragma unroll
  for (int c = 0; c < 2; ++c) gload_lds16(qsrc[c], QdB + ldsoff[c]);
  __syncthreads();

  const f32x4 zero = {0.f, 0.f, 0.f, 0.f};
  float colp[2][2] = {{0.f, 0.f}, {0.f, 0.f}};
  int cur = 0;
  for (int lt = 0; lt < 16; ++lt) {
    if (lt < 15) {   // async prefetch into other buffer; drained at barrier
#pragma unroll
      for (int c = 0; c < 2; ++c)
        gload_lds16(qsrc[c] + (long long)(lt + 1) * 64 * HD,
                    QdB + ((cur ^ 1) << 13) + ldsoff[c]);
    }
    bf16x8 a0k[2], a1k[2];
#pragma unroll
    for (int kh = 0; kh < 2; ++kh) {
      int byt = ((kh << 6) + (quad << 4)) ^ swz;
      a0k[kh] = *(bf16x8*)(QdB + (cur << 13) + (wm + m16) * 128 + byt);
      a1k[kh] = *(bf16x8*)(QdB + (cur << 13) + (wm + 16 + m16) * 128 + byt);
    }
    f32x4 s[2][2][2];
#pragma unroll
    for (int g = 0; g < 2; ++g)
#pragma unroll
      for (int mi = 0; mi < 2; ++mi)
#pragma unroll
        for (int ni = 0; ni < 2; ++ni) s[g][mi][ni] = zero;
    __builtin_amdgcn_s_setprio(1);
#pragma unroll
    for (int g = 0; g < 2; ++g)
#pragma unroll
      for (int kh = 0; kh < 2; ++kh) {
        s[g][0][0] = MFMA(a0k[kh], bk[g][0][kh], s[g][0][0]);
        s[g][0][1] = MFMA(a0k[kh], bk[g][1][kh], s[g][0][1]);
        s[g][1][0] = MFMA(a1k[kh], bk[g][0][kh], s[g][1][0]);
        s[g][1][1] = MFMA(a1k[kh], bk[g][1][kh], s[g][1][1]);
      }
    __builtin_amdgcn_s_setprio(0);
#pragma unroll
    for (int g = 0; g < 2; ++g)
#pragma unroll
      for (int mi = 0; mi < 2; ++mi)
#pragma unroll
        for (int ni = 0; ni < 2; ++ni)
#pragma unroll
          for (int r = 0; r < 4; ++r)
            colp[g][ni] += exp2n(s[g][mi][ni][r]);
    __syncthreads();          // the ONLY barrier (also drains prefetch)
    cur ^= 1;
  }
#pragma unroll
  for (int g = 0; g < 2; ++g)
#pragma unroll
    for (int ni = 0; ni < 2; ++ni) {
      float v = colp[g][ni];
      v += __shfl_down(v, 32, 64);
      v += __shfl_down(v, 16, 64);
      if (quad == 0) cpart[(g << 6) + wn + (ni << 4) + m16][wm >> 5] = v;
    }
  __syncthreads();
  if (t < 128) csum[b * SK + st0 + t] = cpart[t][0] + cpart[t][1];
}

// ================= fused flash: mem + main + gate combine, K/V double-buffer =====
// (round-6 proven structure: reg-staged K/V dbuf, 2 barriers/iter, cross-wave P
// with packed 8B writes + XOR swizzle; exp -> native exp2 via pre-scaled Q)
__global__ __launch_bounds__(256) void attn_fused(
    const bf16* __restrict__ Qh, const bf16* __restrict__ Kh,
    const bf16* __restrict__ Vt, const bf16* __restrict__ km,
    const bf16* __restrict__ vmt, const float* __restrict__ csum,
    const float* __restrict__ Vsum, const int* __restrict__ mask,
    const float* __restrict__ gate, bf16* __restrict__ comb)
{
  __shared__ __align__(16) __bf16 Kd[2][64][72];
  __shared__ __align__(16) __bf16 Vd[2][64][72];
  __shared__ __align__(16) __bf16 Ps[4096];   // [64][64] swizzled
  __shared__ __align__(16) float rcs[SK];
  __shared__ __align__(16) float mskf[MMEM];
  const int bid = blockIdx.y * gridDim.x + blockIdx.x;   // 0..1023
  const int xcd = bid & 7, sub = bid >> 3;               // sub in [0,128)
  const int b = (xcd << 3) + (sub >> 4);                 // 0..63
  const int tm0 = (sub & 15) << 6;
  const int n = b >> 3, h = b & 7;
  const int t = threadIdx.x;
  const int lrow = t >> 2, lcol = (t & 3) << 4;
  const int wave = t >> 6, lane = t & 63;
  const int wm = (wave & 1) << 5, wn = (wave >> 1) << 5;
  const int m16 = lane & 15, quad = lane >> 4;
  const int swz = (m16 & 7) << 4;
  __shared__ float rpa[64][2];
  __shared__ float rpm[64][2];

#pragma unroll
  for (int i = 0; i < 4; ++i)
    rcs[t + i * 256] = 1.f / csum[b * SK + t + i * 256];
  mskf[t] = mask[n * MMEM + t] ? 0.f : 1.f;
  {
    const bf16* qp = Qh + ((long long)b * LQ + tm0 + lrow) * HD + lcol;
    *(bf16x8*)&Kd[0][lrow][lcol] = *(const bf16x8*)qp;
    *(bf16x8*)&Kd[0][lrow][lcol + 8] = *(const bf16x8*)(qp + 8);
  }
  __syncthreads();
  bf16x8 aq[2][2];
#pragma unroll
  for (int li = 0; li < 2; ++li)
#pragma unroll
    for (int kh = 0; kh < 2; ++kh)
      aq[li][kh] = *(bf16x8*)&Kd[0][wm + (li << 4) + m16][(kh << 5) + (quad << 3)];

  const bf16* kbase_m = km + ((long long)b * MMEM + lrow) * HD + lcol;
  const bf16* vbase_m = vmt + ((long long)b * HD + lrow) * MMEM + lcol;
  // stage mem tile 0 into buf1 (Kd[0] still being read above -> different buf)
  {
    bf16x8 k0 = *(const bf16x8*)kbase_m;
    bf16x8 k1 = *(const bf16x8*)(kbase_m + 8);
    bf16x8 v0 = *(const bf16x8*)vbase_m;
    bf16x8 v1 = *(const bf16x8*)(vbase_m + 8);
    *(bf16x8*)&Kd[1][lrow][lcol] = k0;
    *(bf16x8*)&Kd[1][lrow][lcol + 8] = k1;
    *(bf16x8*)&Vd[1][lrow][lcol] = v0;
    *(bf16x8*)&Vd[1][lrow][lcol + 8] = v1;
  }
  __syncthreads();

  const f32x4 zero = {0.f, 0.f, 0.f, 0.f};
  // ---------------- mem branch (4 tiles of km/vmt) ----------------
  f32x4 m00 = zero, m01 = zero, m10 = zero, m11 = zero;
  float rsm[2] = {0.f, 0.f};
  int cur = 1;
  for (int mt = 0; mt < 4; ++mt) {
    bf16x8 kr0, kr1, vr0, vr1;
    if (mt < 3) {
      const bf16* kp = kbase_m + (long long)((mt + 1) << 6) * HD;
      const bf16* vp = vbase_m + ((mt + 1) << 6);
      kr0 = *(const bf16x8*)kp;
      kr1 = *(const bf16x8*)(kp + 8);
      vr0 = *(const bf16x8*)vp;
      vr1 = *(const bf16x8*)(vp + 8);
    }
    f32x4 s00 = zero, s01 = zero, s10 = zero, s11 = zero;
    __builtin_amdgcn_s_setprio(1);
#pragma unroll
    for (int kh = 0; kh < 2; ++kh) {
      bf16x8 ak0 = *(bf16x8*)&Kd[cur][wn + m16][(kh << 5) + (quad << 3)];
      bf16x8 ak1 = *(bf16x8*)&Kd[cur][wn + 16 + m16][(kh << 5) + (quad << 3)];
      s00 = MFMA(ak0, aq[0][kh], s00);
      s01 = MFMA(ak0, aq[1][kh], s01);
      s10 = MFMA(ak1, aq[0][kh], s10);
      s11 = MFMA(ak1, aq[1][kh], s11);
    }
    __builtin_amdgcn_s_setprio(0);
    {
      char* pA = (char*)Ps + (wm + m16) * 128;
      char* pB = (char*)Ps + (wm + 16 + m16) * 128;
#pragma unroll
      for (int si = 0; si < 2; ++si) {
        int sloc = wn + (si << 4) + (quad << 2);
        f32x4 mf4 = *(const f32x4*)&mskf[(mt << 6) + sloc];
        f32x4 sA = si ? s10 : s00;
        f32x4 sB = si ? s11 : s01;
        __bf16 vA[4], vB[4];
#pragma unroll
        for (int r = 0; r < 4; ++r) {
          float pa = exp2n(sA[r]) * mf4[r];
          rsm[0] += pa; vA[r] = tobf(pa);
          float pb = exp2n(sB[r]) * mf4[r];
          rsm[1] += pb; vB[r] = tobf(pb);
        }
        int sbyte = (sloc << 1) ^ swz;
        *(uint2*)(pA + sbyte) = *(uint2*)vA;
        *(uint2*)(pB + sbyte) = *(uint2*)vB;
      }
    }
    __syncthreads();   // B2: P visible; all reads of Kd[cur] (QK) done
    if (mt < 3) {      // stage next tile into the idle buffer
      *(bf16x8*)&Kd[cur ^ 1][lrow][lcol] = kr0;
      *(bf16x8*)&Kd[cur ^ 1][lrow][lcol + 8] = kr1;
      *(bf16x8*)&Vd[cur ^ 1][lrow][lcol] = vr0;
      *(bf16x8*)&Vd[cur ^ 1][lrow][lcol + 8] = vr1;
    }
    __builtin_amdgcn_s_setprio(1);
#pragma unroll
    for (int kh = 0; kh < 2; ++kh) {
      int sb = (kh << 6) + (quad << 4);
      bf16x8 ap0 = *(bf16x8*)((char*)Ps + (wm + m16) * 128 + (sb ^ swz));
      bf16x8 ap1 = *(bf16x8*)((char*)Ps + (wm + 16 + m16) * 128 + (sb ^ swz));
      bf16x8 bv0 = *(bf16x8*)&Vd[cur][wn + m16][(kh << 5) + (quad << 3)];
      bf16x8 bv1 = *(bf16x8*)&Vd[cur][wn + 16 + m16][(kh << 5) + (quad << 3)];
      m00 = MFMA(ap0, bv0, m00);
      m01 = MFMA(ap0, bv1, m01);
      m10 = MFMA(ap1, bv0, m10);
      m11 = MFMA(ap1, bv1, m11);
    }
    __builtin_amdgcn_s_setprio(0);
    __syncthreads();   // B3: PV done; staged tile + Ps safe for next iter
    cur ^= 1;
  }

  // ---------------- main branch (16 tiles of Kh/Vt) ----------------
  f32x4 o00 = zero, o01 = zero, o10 = zero, o11 = zero;
  float rsa[2] = {0.f, 0.f};
  const bf16* kbase = Kh + ((long long)b * SK + lrow) * HD + lcol;
  const bf16* vbase = Vt + ((long long)b * HD + lrow) * SK + lcol;
  {  // stage main tile 0 into buf1 (last mem iter read buf0; buf1 idle)
    bf16x8 k0 = *(const bf16x8*)kbase;
    bf16x8 k1 = *(const bf16x8*)(kbase + 8);
    bf16x8 v0 = *(const bf16x8*)vbase;
    bf16x8 v1 = *(const bf16x8*)(vbase + 8);
    *(bf16x8*)&Kd[1][lrow][lcol] = k0;
    *(bf16x8*)&Kd[1][lrow][lcol + 8] = k1;
    *(bf16x8*)&Vd[1][lrow][lcol] = v0;
    *(bf16x8*)&Vd[1][lrow][lcol + 8] = v1;
  }
  __syncthreads();
  cur = 1;
  for (int st = 0; st < 16; ++st) {
    bf16x8 kr0, kr1, vr0, vr1;
    if (st < 15) {
      const bf16* kp = kbase + (long long)((st + 1) << 6) * HD;
      const bf16* vp = vbase + ((st + 1) << 6);
      kr0 = *(const bf16x8*)kp;
      kr1 = *(const bf16x8*)(kp + 8);
      vr0 = *(const bf16x8*)vp;
      vr1 = *(const bf16x8*)(vp + 8);
    }
    f32x4 s00 = zero, s01 = zero, s10 = zero, s11 = zero;
    __builtin_amdgcn_s_setprio(1);
#pragma unroll
    for (int kh = 0; kh < 2; ++kh) {
      bf16x8 ak0 = *(bf16x8*)&Kd[cur][wn + m16][(kh << 5) + (quad << 3)];
      bf16x8 ak1 = *(bf16x8*)&Kd[cur][wn + 16 + m16][(kh << 5) + (quad << 3)];
      s00 = MFMA(ak0, aq[0][kh], s00);
      s01 = MFMA(ak0, aq[1][kh], s01);
      s10 = MFMA(ak1, aq[0][kh], s10);
      s11 = MFMA(ak1, aq[1][kh], s11);
    }
    __builtin_amdgcn_s_setprio(0);
    {
      char* pA = (char*)Ps + (wm + m16) * 128;
      char* pB = (char*)Ps + (wm + 16 + m16) * 128;
#pragma unroll
      for (int si = 0; si < 2; ++si) {
        int sloc = wn + (si << 4) + (quad << 2);
        f32x4 rc4 = *(const f32x4*)&rcs[(st << 6) + sloc];
        f32x4 sA = si ? s10 : s00;
        f32x4 sB = si ? s11 : s01;
        __bf16 vA[4], vB[4];
#pragma unroll
        for (int r = 0; r < 4; ++r) {
          float pa = exp2n(sA[r]) * rc4[r];
          rsa[0] += pa; vA[r] = tobf(pa);
          float pb = exp2n(sB[r]) * rc4[r];
          rsa[1] += pb; vB[r] = tobf(pb);
        }
        int sbyte = (sloc << 1) ^ swz;
        *(uint2*)(pA + sbyte) = *(uint2*)vA;
        *(uint2*)(pB + sbyte) = *(uint2*)vB;
      }
    }
    __syncthreads();   // B2
    if (st < 15) {
      *(bf16x8*)&Kd[cur ^ 1][lrow][lcol] = kr0;
      *(bf16x8*)&Kd[cur ^ 1][lrow][lcol + 8] = kr1;
      *(bf16x8*)&Vd[cur ^ 1][lrow][lcol] = vr0;
      *(bf16x8*)&Vd[cur ^ 1][lrow][lcol + 8] = vr1;
    }
    __builtin_amdgcn_s_setprio(1);
#pragma unroll
    for (int kh = 0; kh < 2; ++kh) {
      int sb = (kh << 6) + (quad << 4);
      bf16x8 ap0 = *(bf16x8*)((char*)Ps + (wm + m16) * 128 + (sb ^ swz));
      bf16x8 ap1 = *(bf16x8*)((char*)Ps + (wm + 16 + m16) * 128 + (sb ^ swz));
      bf16x8 bv0 = *(bf16x8*)&Vd[cur][wn + m16][(kh << 5) + (quad << 3)];
      bf16x8 bv1 = *(bf16x8*)&Vd[cur][wn + 16 + m16][(kh << 5) + (quad << 3)];
      o00 = MFMA(ap0, bv0, o00);
      o01 = MFMA(ap0, bv1, o01);
      o10 = MFMA(ap1, bv0, o10);
      o11 = MFMA(ap1, bv1, o11);
    }
    __builtin_amdgcn_s_setprio(0);
    __syncthreads();   // B3
    cur ^= 1;
  }

  // ---------------- reductions (both branches) ----------------
#pragma unroll
  for (int li = 0; li < 2; ++li) {
    float va = rsa[li];
    va += __shfl_xor(va, 16, 64);
    va += __shfl_xor(va, 32, 64);
    float vm = rsm[li];
    vm += __shfl_xor(vm, 16, 64);
    vm += __shfl_xor(vm, 32, 64);
    if (quad == 0) {
      rpa[wm + (li << 4) + m16][wn >> 5] = va;
      rpm[wm + (li << 4) + m16][wn >> 5] = vm;
    }
  }
  __syncthreads();

  // ---------------- gate combine in f32, single bf16 write ----------------
  const float* vs = Vsum + b * HD;
  const float g = 1.f / (1.f + __expf(-gate[h]));
  f32x4 oacc[2][2] = {{o00, o01}, {o10, o11}};
  f32x4 macc[2][2] = {{m00, m01}, {m10, m11}};
  for (int mi = 0; mi < 2; ++mi)
    for (int ni = 0; ni < 2; ++ni) {
      int col = wn + (ni << 4) + m16;
      float vsc = 1e-8f * vs[col];
      for (int r = 0; r < 4; ++r) {
        int row = wm + (mi << 4) + (quad << 2) + r;
        float ra = rpa[row][0] + rpa[row][1];
        float rm = rpm[row][0] + rpm[row][1];
        float oa = (oacc[mi][ni][r] + vsc) / (ra + (float)SK * 1e-8f);
        float om = macc[mi][ni][r] / rm;
        Kd[0][row][col] = tobf(g * om + (1.f - g) * oa);
      }
    }
  __syncthreads();
  uint4 u0 = *(uint4*)&Kd[0][lrow][lcol];
  uint4 u1 = *(uint4*)&Kd[0][lrow][lcol + 8];
  long long gb = ((long long)b * LQ + tm0 + lrow) * HD + lcol;
  *(uint4*)(comb + gb) = u0;
  *(uint4*)(comb + gb + 8) = u1;
}

// ================= out proj, m97-structure (A = fused comb buffer) ===============
__global__ __launch_bounds__(256) void gemm_out(
    const bf16* __restrict__ comb, const bf16* __restrict__ opwb,
    const float* __restrict__ opb, float* __restrict__ out)
{
  __shared__ __align__(16) char smem[32768];
  __bf16* As = (__bf16*)smem;             // [128][64] linear
  __bf16* Bs = (__bf16*)(smem + 16384);   // [128][64] linear
  const int bid2 = blockIdx.y * gridDim.x + blockIdx.x;  // 0..255
  const int xcd = bid2 & 7, sub = bid2 >> 3;             // sub in [0,32)
  const int by = (xcd << 3) + (sub >> 2);                // 0..63
  const int bx = sub & 3;                                // 0..3
  const int tm0 = by << 7, tn0 = bx << 7;
  const int t = threadIdx.x;
  const int wave = t >> 6, lane = t & 63;
  const int wrow0 = (wave & 1) << 6, wcol0 = (wave >> 1) << 6;
  const int m16 = lane & 15, quad = lane >> 4;

  const f32x4 zero = {0.f, 0.f, 0.f, 0.f};
  f32x4 acc[4][4];
#pragma unroll
  for (int mi = 0; mi < 4; ++mi)
#pragma unroll
    for (int ni = 0; ni < 4; ++ni) acc[mi][ni] = zero;

  const bf16* Bb = opwb + (long long)tn0 * EE;
  const int ob_u = wave << 10;

  for (int k0 = 0; k0 < EE; k0 += 64) {
    const int h = k0 >> 6;
#pragma unroll
    for (int c = 0; c < 4; ++c) {
      int ob = (c << 12) + ob_u;
      int obl = ob + (lane << 4);
      int row = obl >> 7;
      int ce = (obl & 127) >> 1;
      int arow = tm0 + row;
      int l = arow >> 3, nn = arow & 7;
      gload_lds16(comb + (((long long)(nn * NH + h) * LQ + l) * HD + ce),
                  smem + ob);
      gload_lds16(Bb + (long long)row * EE + k0 + ce, smem + 16384 + ob);
    }
    __syncthreads();
#pragma unroll
    for (int kh = 0; kh < 2; ++kh) {
      bf16x8 av[4], bv[4];
#pragma unroll
      for (int i = 0; i < 4; ++i) {
        av[i] = *(bf16x8*)(As + ((wrow0 + (i << 4) + m16) << 6) + (kh << 5) + (quad << 3));
        bv[i] = *(bf16x8*)(Bs + ((wcol0 + (i << 4) + m16) << 6) + (kh << 5) + (quad << 3));
      }
#pragma unroll
      for (int mi = 0; mi < 4; ++mi)
#pragma unroll
        for (int ni = 0; ni < 4; ++ni)
          acc[mi][ni] = MFMA(av[mi], bv[ni], acc[mi][ni]);
    }
    __syncthreads();
  }

#pragma unroll
  for (int mi = 0; mi < 4; ++mi)
#pragma unroll
    for (int ni = 0; ni < 4; ++ni) {
      int col = tn0 + wcol0 + (ni << 4) + m16;
      float bv = opb[col];
      int row0 = tm0 + wrow0 + (mi << 4) + (quad << 2);
#pragma unroll
      for (int r = 0; r < 4; ++r)
        out[(long long)(row0 + r) * EE + col] = acc[mi][ni][r] + bv;
    }
}

// ================= LDS-tiled transposes (no 2B-granular scatter) =================
__global__ __launch_bounds__(256) void v_transpose(
    const bf16* __restrict__ raw, bf16* __restrict__ Vt,
    float* __restrict__ Vsum)
{
  __shared__ __align__(16) __bf16 Ts[64][72];
  const int bh = blockIdx.y;             // n*NH + h
  const int n = bh >> 3, h = bh & 7;
  const int s0 = blockIdx.x << 6;
  const int t = threadIdx.x;
  const int i = t >> 2, c0 = (t & 3) << 4;
  const bf16* rp = raw + ((long long)(s0 + i) * NB + n) * EE + h * HD + c0;
  *(bf16x8*)&Ts[i][c0] = *(const bf16x8*)rp;
  *(bf16x8*)&Ts[i][c0 + 8] = *(const bf16x8*)(rp + 8);
  __syncthreads();
  const int d = t >> 2, j0 = (t & 3) << 4;
  __bf16 vals[16];
  float part = 0.f;
#pragma unroll
  for (int j = 0; j < 16; ++j) { vals[j] = Ts[j0 + j][d]; part += bf2f(vals[j]); }
  bf16* wp = Vt + ((long long)bh * HD + d) * SK + s0 + j0;
  *(uint4*)wp = *(uint4*)&vals[0];
  *(uint4*)(wp + 8) = *(uint4*)&vals[8];
  part += __shfl_xor(part, 1, 64);
  part += __shfl_xor(part, 2, 64);
  if ((t & 3) == 0) atomicAdd(&Vsum[bh * HD + d], part);
}

__global__ __launch_bounds__(256) void mem_prep(
    const float* __restrict__ k_mem, const float* __restrict__ v_mem,
    bf16* __restrict__ km, bf16* __restrict__ vmt)
{
  __shared__ __align__(16) __bf16 Ts[64][72];
  const int bh = blockIdx.y;             // n*NH + h
  const int n = bh >> 3, h = bh & 7;
  const int m0 = blockIdx.x << 6;
  const int t = threadIdx.x;
  const int i = t >> 2, c0 = (t & 3) << 4;
  const float* kp = k_mem + ((long long)(m0 + i) * NB + n) * EE + h * HD + c0;
  const float* vp = v_mem + ((long long)(m0 + i) * NB + n) * EE + h * HD + c0;
  bf16x8 kv0 = load8(kp), kv1 = load8(kp + 8);
  bf16x8 vv0 = load8(vp), vv1 = load8(vp + 8);
  bf16* kw = km + ((long long)bh * MMEM + m0 + i) * HD + c0;
  *(bf16x8*)kw = kv0;
  *(bf16x8*)(kw + 8) = kv1;
  *(bf16x8*)&Ts[i][c0] = vv0;
  *(bf16x8*)&Ts[i][c0 + 8] = vv1;
  __syncthreads();
  const int d = t >> 2, j0 = (t & 3) << 4;
  __bf16 vals[16];
#pragma unroll
  for (int j = 0; j < 16; ++j) vals[j] = Ts[j0 + j][d];
  bf16* wp = vmt + ((long long)bh * HD + d) * MMEM + m0 + j0;
  *(uint4*)wp = *(uint4*)&vals[0];
  *(uint4*)(wp + 8) = *(uint4*)&vals[8];
}

extern "C" void kernel_launch(void* const* d_in, const int* in_sizes, int n_in,
                              void* d_out, int out_size, void* d_ws, size_t ws_size,
                              hipStream_t stream) {
  const float* query = (const float*)d_in[0];
  const float* key   = (const float*)d_in[1];
  const float* value = (const float*)d_in[2];
  const float* ipw   = (const float*)d_in[3];
  const float* ipb   = (const float*)d_in[4];
  const float* opw   = (const float*)d_in[5];
  const float* opb   = (const float*)d_in[6];
  const float* rot_q = (const float*)d_in[7];
  const float* rot_k = (const float*)d_in[8];
  const float* k_mem = (const float*)d_in[9];
  const float* v_mem = (const float*)d_in[10];
  const float* gate  = (const float*)d_in[11];
  const int*  mask   = (const int*)d_in[12];
  float* out = (float*)d_out;

  char* w = (char*)d_ws;
  size_t off = 0;
  auto carve = [&](size_t bytes) -> char* {
    char* p = w + off;
    off += (bytes + 255) & ~(size_t)255;
    return p;
  };
  bf16* qc    = (bf16*)carve((size_t)LQ * NB * EE * 2);
  bf16* kc    = (bf16*)carve((size_t)SK * NB * EE * 2);
  bf16* vc    = (bf16*)carve((size_t)SK * NB * EE * 2);
  bf16* ipwb  = (bf16*)carve((size_t)3 * EE * EE * 2);
  bf16* opwb  = (bf16*)carve((size_t)EE * EE * 2);
  bf16* v_raw = (bf16*)carve((size_t)SK * NB * EE * 2);
  bf16* Qh    = (bf16*)carve((size_t)NBH * LQ * HD * 2);
  bf16* Kh    = (bf16*)carve((size_t)NBH * SK * HD * 2);
  bf16* Vt    = (bf16*)carve((size_t)NBH * HD * SK * 2);
  bf16* km    = (bf16*)carve((size_t)NBH * MMEM * HD * 2);
  bf16* vmt   = (bf16*)carve((size_t)NBH * HD * MMEM * 2);
  float* csum = (float*)carve((size_t)NBH * SK * 4);
  float* Vsum = (float*)carve((size_t)NBH * HD * 4);
  bf16* comb  = (bf16*)carve((size_t)NBH * LQ * HD * 2);
  bf16* pkbuf = (bf16*)carve((size_t)NBH * LQ * HD * 2);
  if (off > ws_size) {
    hipMemsetAsync(d_out, 0, (size_t)out_size * 4, stream);
    return;
  }
  // pq aliases comb: comb is only written by attn_fused, well after rotary
  // consumed pq. pkbuf is rotary's K staging.
  bf16* pq = comb;
  bf16* pk = pkbuf;

  // 0) pre-convert GEMM inputs to bf16; zero Vsum accumulators
  convert5<<<(3 * CVT_T0 + CVT_T3 + CVT_T4) / 256, 256, 0, stream>>>(
      query, key, value, ipw, opw, qc, kc, vc, ipwb, opwb);
  hipMemsetAsync(Vsum, 0, (size_t)NBH * HD * 4, stream);

  // 1) q/k/v projections (q alpha folds log2e for exp2 softmax downstream)
  gemm_proj3<<<dim3(EE / 128, (LQ * NB) / 128, 3), 256, 0, stream>>>(
      qc, kc, vc, ipwb, ipb, pq, pk, v_raw);

  // 1b) rotary + head reshape as a pure streaming kernel
  rotary_kernel<<<dim3((LQ * NB) / 4, 2), 256, 0, stream>>>(
      pq, pk, rot_q, rot_k, Qh, Kh);

  // 2) v transpose (LDS-tiled, fused Vsum atomics); mem k/v repack
  v_transpose<<<dim3(SK / 64, NBH), 256, 0, stream>>>(v_raw, Vt, Vsum);
  mem_prep<<<dim3(MMEM / 64, NBH), 256, 0, stream>>>(k_mem, v_mem, km, vmt);

  // 3) column sums (128 cols/block, gload_lds Q-dbuf, 1 barrier/iter, exp2)
  colsum_kernel<<<dim3(SK / 128, NBH), 256, 0, stream>>>(Qh, Kh, csum);

  // 4) fused flash (round-6 structure: K/V reg-dbuf, 2 barriers/iter, exp2)
  attn_fused<<<dim3(LQ / 64, NBH), 256, 0, stream>>>(
      Qh, Kh, Vt, km, vmt, csum, Vsum, mask, gate, comb);

  // 5) out-proj, m97 structure, single A buffer
  gemm_out<<<dim3(4, 64), 256, 0, stream>>>(comb, opwb, opb, out);
}

// Round 12
// 291.428 us; speedup vs baseline: 1.1787x; 1.0281x over previous
//
#include <hip/hip_runtime.h>
#include <hip/hip_bf16.h>

typedef __hip_bfloat16 bf16;
typedef __bf16 bf16x8 __attribute__((ext_vector_type(8)));
typedef float f32x4 __attribute__((ext_vector_type(4)));

#define LQ 1024
#define SK 1024
#define MMEM 256
#define NB 8
#define EE 512
#define NH 8
#define HD 64
#define NBH 64  // NB*NH batched (n,h) pairs

__device__ inline __bf16 tobf(float f) {
  __hip_bfloat16 h = __float2bfloat16(f);
  return *reinterpret_cast<__bf16*>(&h);
}
__device__ inline float bf2f(__bf16 x) {
  unsigned short u; __builtin_memcpy(&u, &x, 2);
  unsigned int v = (unsigned int)u << 16;
  float f; __builtin_memcpy(&f, &v, 4);
  return f;
}
__device__ inline f32x4 MFMA(bf16x8 a, bf16x8 b, f32x4 c) {
  return __builtin_amdgcn_mfma_f32_16x16x32_bf16(a, b, c, 0, 0, 0);
}
// native 2^x (single v_exp_f32, no libm fixup code -- exp2f pulls in the
// correctly-rounded OCML path which cost +16 VGPR and an occupancy tier)
__device__ inline float exp2n(float x) { return __builtin_amdgcn_exp2f(x); }

// async global->LDS, 16B per lane. LDS dest is wave-uniform base + lane*16.
__device__ inline void gload_lds16(const bf16* g, void* l) {
  __builtin_amdgcn_global_load_lds(
      (const __attribute__((address_space(1))) void*)g,
      (__attribute__((address_space(3))) void*)l, 16, 0, 0);
}

__device__ inline bf16x8 load8(const float* p) {
  float4 a = *(const float4*)p;
  float4 b = *(const float4*)(p + 4);
  bf16x8 r;
  r[0] = tobf(a.x); r[1] = tobf(a.y); r[2] = tobf(a.z); r[3] = tobf(a.w);
  r[4] = tobf(b.x); r[5] = tobf(b.y); r[6] = tobf(b.z); r[7] = tobf(b.w);
  return r;
}

// ================= bf16 pre-conversion of GEMM inputs (+ Vsum zero) ==============
#define CVT_T0 524288   // threads per q/k/v region (8 elems each)
#define CVT_T3 98304    // ipw
#define CVT_T4 32768    // opw
__global__ __launch_bounds__(256) void convert5(
    const float* __restrict__ q, const float* __restrict__ k,
    const float* __restrict__ v, const float* __restrict__ w,
    const float* __restrict__ o, bf16* __restrict__ qc, bf16* __restrict__ kc,
    bf16* __restrict__ vc, bf16* __restrict__ wc, bf16* __restrict__ oc,
    float* __restrict__ Vsum)
{
  long long t = (long long)blockIdx.x * 256 + threadIdx.x;
  if (blockIdx.x == 0) {   // fold the Vsum memset into this first kernel
#pragma unroll
    for (int i = 0; i < (NBH * HD) / 256; ++i)
      Vsum[threadIdx.x + i * 256] = 0.f;
  }
  const float* src; bf16* dst; long long idx;
  if (t < CVT_T0)               { src = q; dst = qc; idx = t; }
  else if (t < 2 * CVT_T0)      { src = k; dst = kc; idx = t - CVT_T0; }
  else if (t < 3 * CVT_T0)      { src = v; dst = vc; idx = t - 2 * CVT_T0; }
  else if (t < 3 * CVT_T0 + CVT_T3) { src = w; dst = wc; idx = t - 3 * CVT_T0; }
  else                          { src = o; dst = oc; idx = t - 3 * CVT_T0 - CVT_T3; }
  *(bf16x8*)(dst + idx * 8) = load8(src + idx * 8);
}

// ================= 3-in-1 projection GEMM, m97-structure, PURE GEMM ==============
// z=0 alpha folds log2e so downstream softmax uses native exp2 (saves one v_mul
// per exp in colsum + attn, all mathematically identical: exp(S)=2^(S*log2e)).
__global__ __launch_bounds__(256) void gemm_proj3(
    const bf16* __restrict__ qc, const bf16* __restrict__ kc,
    const bf16* __restrict__ vc, const bf16* __restrict__ ipwb,
    const float* __restrict__ ipb, bf16* __restrict__ pq,
    bf16* __restrict__ pk, bf16* __restrict__ v_raw)
{
  __shared__ __align__(16) char smem[33792];
  __bf16* As = (__bf16*)smem;             // [128][64] linear, 16384 B
  __bf16* Bs = (__bf16*)(smem + 16384);   // [128][64] linear, 16384 B
  const int z = blockIdx.z;
  const bf16* A = (z == 0) ? qc : (z == 1) ? kc : vc;
  const bf16* W = ipwb + (long long)z * EE * EE;
  const float* bias = ipb + z * EE;
  const float alpha = (z == 0) ? 0.1803368801f : 1.f;  // 0.125 * log2(e)
  const int bid2 = blockIdx.y * gridDim.x + blockIdx.x;
  const int xcd = bid2 & 7, sub = bid2 >> 3;       // sub in [0,32)
  const int by = (xcd << 3) + (sub >> 2);          // 0..63
  const int bx = sub & 3;                          // 0..3
  const int tm0 = by << 7, tn0 = bx << 7;          // 128 x 128
  const int t = threadIdx.x;
  const int wave = t >> 6, lane = t & 63;
  const int wrow0 = (wave & 1) << 6, wcol0 = (wave >> 1) << 6;
  const int m16 = lane & 15, quad = lane >> 4;

  const f32x4 zero = {0.f, 0.f, 0.f, 0.f};
  f32x4 acc[4][4];
#pragma unroll
  for (int mi = 0; mi < 4; ++mi)
#pragma unroll
    for (int ni = 0; ni < 4; ++ni) acc[mi][ni] = zero;

  const bf16* Ab = A + (long long)tm0 * EE;
  const bf16* Bb = W + (long long)tn0 * EE;
  const int ob_u = wave << 10;  // wave-uniform byte base within 4KB chunk

  for (int k0 = 0; k0 < EE; k0 += 64) {
#pragma unroll
    for (int c = 0; c < 4; ++c) {
      int ob = (c << 12) + ob_u;          // uniform LDS byte base
      int obl = ob + (lane << 4);         // this lane's slot
      int row = obl >> 7;                 // tile row (stride 128 B)
      int ce = (obl & 127) >> 1;          // element within row
      gload_lds16(Ab + (long long)row * EE + k0 + ce, smem + ob);
      gload_lds16(Bb + (long long)row * EE + k0 + ce, smem + 16384 + ob);
    }
    __syncthreads();
#pragma unroll
    for (int kh = 0; kh < 2; ++kh) {
      bf16x8 av[4], bv[4];
#pragma unroll
      for (int i = 0; i < 4; ++i) {
        av[i] = *(bf16x8*)(As + ((wrow0 + (i << 4) + m16) << 6) + (kh << 5) + (quad << 3));
        bv[i] = *(bf16x8*)(Bs + ((wcol0 + (i << 4) + m16) << 6) + (kh << 5) + (quad << 3));
      }
#pragma unroll
      for (int mi = 0; mi < 4; ++mi)
#pragma unroll
        for (int ni = 0; ni < 4; ++ni)
          acc[mi][ni] = MFMA(av[mi], bv[ni], acc[mi][ni]);
    }
    __syncthreads();
  }

  __bf16 (*Cs)[132] = (__bf16(*)[132])smem;
#pragma unroll
  for (int mi = 0; mi < 4; ++mi)
#pragma unroll
    for (int ni = 0; ni < 4; ++ni) {
      int col = wcol0 + (ni << 4) + m16;
      float bv = bias[tn0 + col];
#pragma unroll
      for (int r = 0; r < 4; ++r)
        Cs[wrow0 + (mi << 4) + (quad << 2) + r][col] =
            tobf((acc[mi][ni][r] + bv) * alpha);
    }
  __syncthreads();
  bf16* O = (z == 0) ? pq : (z == 1) ? pk : v_raw;
  const int crow = t >> 1, ch0 = (t & 1) << 6;   // 2 threads/row, 64 cols each
  long long gb = (long long)(tm0 + crow) * EE + tn0 + ch0;
#pragma unroll
  for (int j = 0; j < 64; j += 8)
    *(uint4*)(O + gb + j) = *(uint4*)&Cs[crow][ch0 + j];
}

// ================= merged prep: rotary + v_transpose + mem_prep ==================
// One launch, branch on linear block id (block-uniform; saves 2 graph nodes).
//   [0, 4096)      rotary: y = bid>>11, x = bid&2047
//   [4096, 5120)   v_transpose: bh = v>>4, s-tile = v&15
//   [5120, 5376)   mem_prep:    bh = v>>2, m-tile = v&3
__global__ __launch_bounds__(256) void prep_all(
    const bf16* __restrict__ pq, const bf16* __restrict__ pk,
    const float* __restrict__ rot_q, const float* __restrict__ rot_k,
    bf16* __restrict__ Qh, bf16* __restrict__ Kh,
    const bf16* __restrict__ v_raw, bf16* __restrict__ Vt,
    float* __restrict__ Vsum,
    const float* __restrict__ k_mem, const float* __restrict__ v_mem,
    bf16* __restrict__ km, bf16* __restrict__ vmt)
{
  __shared__ __align__(16) __bf16 Ts[64][72];
  const int bid = blockIdx.x;
  const int t = threadIdx.x;
  if (bid < 4096) {
    // ---- rotary + head-reshape, pure streaming ----
    const int yy = bid >> 11;
    const int xx = bid & 2047;
    const bf16* src = yy ? pk : pq;
    const float* rot = yy ? rot_k : rot_q;
    bf16* dst = yy ? Kh : Qh;
    const int row = (xx << 2) + (t >> 6);   // l*NB + n
    const int e0 = (t & 63) << 3;           // 8 elems per lane
    const int l = row >> 3, n = row & 7;
    bf16x8 x = *(const bf16x8*)(src + (long long)row * EE + e0);
    const float* rp = rot + ((((long long)n * LQ + l) * EE + e0) << 1);
    __bf16 vals[8];
#pragma unroll
    for (int j = 0; j < 8; j += 2) {
      float4 cs4 = *(const float4*)(rp + (j << 1));  // c0,s0,c1,s1
      float x0 = bf2f(x[j]);
      float x1 = bf2f(x[j + 1]);
      vals[j]     = tobf(x0 * cs4.x - x1 * cs4.y);
      vals[j + 1] = tobf(x1 * cs4.z + x0 * cs4.w);
    }
    const int h = e0 >> 6, d0 = e0 & 63;
    *(uint4*)(dst + (((long long)(n * NH + h) * LQ + l) * HD + d0)) = *(uint4*)vals;
  } else if (bid < 5120) {
    // ---- v transpose (LDS-tiled) + fused Vsum atomics ----
    const int v = bid - 4096;
    const int bh = v >> 4;                 // n*NH + h
    const int n = bh >> 3, h = bh & 7;
    const int s0 = (v & 15) << 6;
    const int i = t >> 2, c0 = (t & 3) << 4;
    const bf16* rp = v_raw + ((long long)(s0 + i) * NB + n) * EE + h * HD + c0;
    *(bf16x8*)&Ts[i][c0] = *(const bf16x8*)rp;
    *(bf16x8*)&Ts[i][c0 + 8] = *(const bf16x8*)(rp + 8);
    __syncthreads();
    const int d = t >> 2, j0 = (t & 3) << 4;
    __bf16 vals[16];
    float part = 0.f;
#pragma unroll
    for (int j = 0; j < 16; ++j) { vals[j] = Ts[j0 + j][d]; part += bf2f(vals[j]); }
    bf16* wp = Vt + ((long long)bh * HD + d) * SK + s0 + j0;
    *(uint4*)wp = *(uint4*)&vals[0];
    *(uint4*)(wp + 8) = *(uint4*)&vals[8];
    part += __shfl_xor(part, 1, 64);
    part += __shfl_xor(part, 2, 64);
    if ((t & 3) == 0) atomicAdd(&Vsum[bh * HD + d], part);
  } else {
    // ---- mem k/v repack (km coalesced + vmt tiled transpose) ----
    const int v = bid - 5120;
    const int bh = v >> 2;                 // n*NH + h
    const int n = bh >> 3, h = bh & 7;
    const int m0 = (v & 3) << 6;
    const int i = t >> 2, c0 = (t & 3) << 4;
    const float* kp = k_mem + ((long long)(m0 + i) * NB + n) * EE + h * HD + c0;
    const float* vp = v_mem + ((long long)(m0 + i) * NB + n) * EE + h * HD + c0;
    bf16x8 kv0 = load8(kp), kv1 = load8(kp + 8);
    bf16x8 vv0 = load8(vp), vv1 = load8(vp + 8);
    bf16* kw = km + ((long long)bh * MMEM + m0 + i) * HD + c0;
    *(bf16x8*)kw = kv0;
    *(bf16x8*)(kw + 8) = kv1;
    *(bf16x8*)&Ts[i][c0] = vv0;
    *(bf16x8*)&Ts[i][c0 + 8] = vv1;
    __syncthreads();
    const int d = t >> 2, j0 = (t & 3) << 4;
    __bf16 vals[16];
#pragma unroll
    for (int j = 0; j < 16; ++j) vals[j] = Ts[j0 + j][d];
    bf16* wp = vmt + ((long long)bh * HD + d) * MMEM + m0 + j0;
    *(uint4*)wp = *(uint4*)&vals[0];
    *(uint4*)(wp + 8) = *(uint4*)&vals[8];
  }
}

// ================= colsum: 128 K-cols/block, gload_lds Q-dbuf, 1 barrier/iter ====
__global__ __launch_bounds__(256) void colsum_kernel(
    const bf16* __restrict__ Qh, const bf16* __restrict__ Kh,
    float* __restrict__ csum)
{
  __shared__ __align__(16) char QdB[16384];   // [2][64][64] bf16 linear
  __shared__ float cpart[128][2];
  const int bid = blockIdx.y * gridDim.x + blockIdx.x;   // 0..511
  const int xcd = bid & 7, sub = bid >> 3;               // sub in [0,64)
  const int b = (xcd << 3) + (sub >> 3);                 // 0..63
  const int st0 = (sub & 7) << 7;                        // 0..896
  const int t = threadIdx.x;
  const int wave = t >> 6, lane = t & 63;
  const int wm = (wave & 1) << 5, wn = (wave >> 1) << 5;
  const int m16 = lane & 15, quad = lane >> 4;
  const int swz = (m16 & 7) << 4;

  // K fragments (8 x 16B direct global loads, one-time)
  bf16x8 bk[2][2][2];  // [g][ni][kh]
#pragma unroll
  for (int g = 0; g < 2; ++g)
#pragma unroll
    for (int ni = 0; ni < 2; ++ni)
#pragma unroll
      for (int kh = 0; kh < 2; ++kh)
        bk[g][ni][kh] = *(const bf16x8*)(
            Kh + ((long long)b * SK + st0 + (g << 6) + wn + (ni << 4) + m16) * HD
               + (kh << 5) + (quad << 3));

  // staging precompute: 2 chunks of 1KB per wave, source-side swizzle
  int ldsoff[2]; const bf16* qsrc[2];
#pragma unroll
  for (int c = 0; c < 2; ++c) {
    int tb = (wave << 11) + (c << 10) + (lane << 4);
    int row = tb >> 7, cb = tb & 127;
    int srcb = cb ^ ((row & 7) << 4);
    ldsoff[c] = (wave << 11) + (c << 10);
    qsrc[c] = Qh + ((long long)b * LQ + row) * HD + (srcb >> 1);
  }
#pragma unroll
  for (int c = 0; c < 2; ++c) gload_lds16(qsrc[c], QdB + ldsoff[c]);
  __syncthreads();

  const f32x4 zero = {0.f, 0.f, 0.f, 0.f};
  float colp[2][2] = {{0.f, 0.f}, {0.f, 0.f}};
  int cur = 0;
  for (int lt = 0; lt < 16; ++lt) {
    if (lt < 15) {   // async prefetch into other buffer; drained at barrier
#pragma unroll
      for (int c = 0; c < 2; ++c)
        gload_lds16(qsrc[c] + (long long)(lt + 1) * 64 * HD,
                    QdB + ((cur ^ 1) << 13) + ldsoff[c]);
    }
    bf16x8 a0k[2], a1k[2];
#pragma unroll
    for (int kh = 0; kh < 2; ++kh) {
      int byt = ((kh << 6) + (quad << 4)) ^ swz;
      a0k[kh] = *(bf16x8*)(QdB + (cur << 13) + (wm + m16) * 128 + byt);
      a1k[kh] = *(bf16x8*)(QdB + (cur << 13) + (wm + 16 + m16) * 128 + byt);
    }
    f32x4 s[2][2][2];
#pragma unroll
    for (int g = 0; g < 2; ++g)
#pragma unroll
      for (int mi = 0; mi < 2; ++mi)
#pragma unroll
        for (int ni = 0; ni < 2; ++ni) s[g][mi][ni] = zero;
    __builtin_amdgcn_s_setprio(1);
#pragma unroll
    for (int g = 0; g < 2; ++g)
#pragma unroll
      for (int kh = 0; kh < 2; ++kh) {
        s[g][0][0] = MFMA(a0k[kh], bk[g][0][kh], s[g][0][0]);
        s[g][0][1] = MFMA(a0k[kh], bk[g][1][kh], s[g][0][1]);
        s[g][1][0] = MFMA(a1k[kh], bk[g][0][kh], s[g][1][0]);
        s[g][1][1] = MFMA(a1k[kh], bk[g][1][kh], s[g][1][1]);
      }
    __builtin_amdgcn_s_setprio(0);
#pragma unroll
    for (int g = 0; g < 2; ++g)
#pragma unroll
      for (int mi = 0; mi < 2; ++mi)
#pragma unroll
        for (int ni = 0; ni < 2; ++ni)
#pragma unroll
          for (int r = 0; r < 4; ++r)
            colp[g][ni] += exp2n(s[g][mi][ni][r]);
    __syncthreads();          // the ONLY barrier (also drains prefetch)
    cur ^= 1;
  }
#pragma unroll
  for (int g = 0; g < 2; ++g)
#pragma unroll
    for (int ni = 0; ni < 2; ++ni) {
      float v = colp[g][ni];
      v += __shfl_down(v, 32, 64);
      v += __shfl_down(v, 16, 64);
      if (quad == 0) cpart[(g << 6) + wn + (ni << 4) + m16][wm >> 5] = v;
    }
  __syncthreads();
  if (t < 128) csum[b * SK + st0 + t] = cpart[t][0] + cpart[t][1];
}

// ================= fused flash: mem + main + gate combine, K/V double-buffer =====
// (round-6 proven structure: reg-staged K/V dbuf, 2 barriers/iter, cross-wave P
// with packed 8B writes + XOR swizzle; exp -> native exp2 via pre-scaled Q)
__global__ __launch_bounds__(256) void attn_fused(
    const bf16* __restrict__ Qh, const bf16* __restrict__ Kh,
    const bf16* __restrict__ Vt, const bf16* __restrict__ km,
    const bf16* __restrict__ vmt, const float* __restrict__ csum,
    const float* __restrict__ Vsum, const int* __restrict__ mask,
    const float* __restrict__ gate, bf16* __restrict__ comb)
{
  __shared__ __align__(16) __bf16 Kd[2][64][72];
  __shared__ __align__(16) __bf16 Vd[2][64][72];
  __shared__ __align__(16) __bf16 Ps[4096];   // [64][64] swizzled
  __shared__ __align__(16) float rcs[SK];
  __shared__ __align__(16) float mskf[MMEM];
  const int bid = blockIdx.y * gridDim.x + blockIdx.x;   // 0..1023
  const int xcd = bid & 7, sub = bid >> 3;               // sub in [0,128)
  const int b = (xcd << 3) + (sub >> 4);                 // 0..63
  const int tm0 = (sub & 15) << 6;
  const int n = b >> 3, h = b & 7;
  const int t = threadIdx.x;
  const int lrow = t >> 2, lcol = (t & 3) << 4;
  const int wave = t >> 6, lane = t & 63;
  const int wm = (wave & 1) << 5, wn = (wave >> 1) << 5;
  const int m16 = lane & 15, quad = lane >> 4;
  const int swz = (m16 & 7) << 4;
  __shared__ float rpa[64][2];
  __shared__ float rpm[64][2];

#pragma unroll
  for (int i = 0; i < 4; ++i)
    rcs[t + i * 256] = 1.f / csum[b * SK + t + i * 256];
  mskf[t] = mask[n * MMEM + t] ? 0.f : 1.f;
  {
    const bf16* qp = Qh + ((long long)b * LQ + tm0 + lrow) * HD + lcol;
    *(bf16x8*)&Kd[0][lrow][lcol] = *(const bf16x8*)qp;
    *(bf16x8*)&Kd[0][lrow][lcol + 8] = *(const bf16x8*)(qp + 8);
  }
  __syncthreads();
  bf16x8 aq[2][2];
#pragma unroll
  for (int li = 0; li < 2; ++li)
#pragma unroll
    for (int kh = 0; kh < 2; ++kh)
      aq[li][kh] = *(bf16x8*)&Kd[0][wm + (li << 4) + m16][(kh << 5) + (quad << 3)];

  const bf16* kbase_m = km + ((long long)b * MMEM + lrow) * HD + lcol;
  const bf16* vbase_m = vmt + ((long long)b * HD + lrow) * MMEM + lcol;
  // stage mem tile 0 into buf1 (Kd[0] still being read above -> different buf)
  {
    bf16x8 k0 = *(const bf16x8*)kbase_m;
    bf16x8 k1 = *(const bf16x8*)(kbase_m + 8);
    bf16x8 v0 = *(const bf16x8*)vbase_m;
    bf16x8 v1 = *(const bf16x8*)(vbase_m + 8);
    *(bf16x8*)&Kd[1][lrow][lcol] = k0;
    *(bf16x8*)&Kd[1][lrow][lcol + 8] = k1;
    *(bf16x8*)&Vd[1][lrow][lcol] = v0;
    *(bf16x8*)&Vd[1][lrow][lcol + 8] = v1;
  }
  __syncthreads();

  const f32x4 zero = {0.f, 0.f, 0.f, 0.f};
  // ---------------- mem branch (4 tiles of km/vmt) ----------------
  f32x4 m00 = zero, m01 = zero, m10 = zero, m11 = zero;
  float rsm[2] = {0.f, 0.f};
  int cur = 1;
  for (int mt = 0; mt < 4; ++mt) {
    bf16x8 kr0, kr1, vr0, vr1;
    if (mt < 3) {
      const bf16* kp = kbase_m + (long long)((mt + 1) << 6) * HD;
      const bf16* vp = vbase_m + ((mt + 1) << 6);
      kr0 = *(const bf16x8*)kp;
      kr1 = *(const bf16x8*)(kp + 8);
      vr0 = *(const bf16x8*)vp;
      vr1 = *(const bf16x8*)(vp + 8);
    }
    f32x4 s00 = zero, s01 = zero, s10 = zero, s11 = zero;
    __builtin_amdgcn_s_setprio(1);
#pragma unroll
    for (int kh = 0; kh < 2; ++kh) {
      bf16x8 ak0 = *(bf16x8*)&Kd[cur][wn + m16][(kh << 5) + (quad << 3)];
      bf16x8 ak1 = *(bf16x8*)&Kd[cur][wn + 16 + m16][(kh << 5) + (quad << 3)];
      s00 = MFMA(ak0, aq[0][kh], s00);
      s01 = MFMA(ak0, aq[1][kh], s01);
      s10 = MFMA(ak1, aq[0][kh], s10);
      s11 = MFMA(ak1, aq[1][kh], s11);
    }
    __builtin_amdgcn_s_setprio(0);
    {
      char* pA = (char*)Ps + (wm + m16) * 128;
      char* pB = (char*)Ps + (wm + 16 + m16) * 128;
#pragma unroll
      for (int si = 0; si < 2; ++si) {
        int sloc = wn + (si << 4) + (quad << 2);
        f32x4 mf4 = *(const f32x4*)&mskf[(mt << 6) + sloc];
        f32x4 sA = si ? s10 : s00;
        f32x4 sB = si ? s11 : s01;
        __bf16 vA[4], vB[4];
#pragma unroll
        for (int r = 0; r < 4; ++r) {
          float pa = exp2n(sA[r]) * mf4[r];
          rsm[0] += pa; vA[r] = tobf(pa);
          float pb = exp2n(sB[r]) * mf4[r];
          rsm[1] += pb; vB[r] = tobf(pb);
        }
        int sbyte = (sloc << 1) ^ swz;
        *(uint2*)(pA + sbyte) = *(uint2*)vA;
        *(uint2*)(pB + sbyte) = *(uint2*)vB;
      }
    }
    __syncthreads();   // B2: P visible; all reads of Kd[cur] (QK) done
    if (mt < 3) {      // stage next tile into the idle buffer
      *(bf16x8*)&Kd[cur ^ 1][lrow][lcol] = kr0;
      *(bf16x8*)&Kd[cur ^ 1][lrow][lcol + 8] = kr1;
      *(bf16x8*)&Vd[cur ^ 1][lrow][lcol] = vr0;
      *(bf16x8*)&Vd[cur ^ 1][lrow][lcol + 8] = vr1;
    }
    __builtin_amdgcn_s_setprio(1);
#pragma unroll
    for (int kh = 0; kh < 2; ++kh) {
      int sb = (kh << 6) + (quad << 4);
      bf16x8 ap0 = *(bf16x8*)((char*)Ps + (wm + m16) * 128 + (sb ^ swz));
      bf16x8 ap1 = *(bf16x8*)((char*)Ps + (wm + 16 + m16) * 128 + (sb ^ swz));
      bf16x8 bv0 = *(bf16x8*)&Vd[cur][wn + m16][(kh << 5) + (quad << 3)];
      bf16x8 bv1 = *(bf16x8*)&Vd[cur][wn + 16 + m16][(kh << 5) + (quad << 3)];
      m00 = MFMA(ap0, bv0, m00);
      m01 = MFMA(ap0, bv1, m01);
      m10 = MFMA(ap1, bv0, m10);
      m11 = MFMA(ap1, bv1, m11);
    }
    __builtin_amdgcn_s_setprio(0);
    __syncthreads();   // B3: PV done; staged tile + Ps safe for next iter
    cur ^= 1;
  }

  // ---------------- main branch (16 tiles of Kh/Vt) ----------------
  f32x4 o00 = zero, o01 = zero, o10 = zero, o11 = zero;
  float rsa[2] = {0.f, 0.f};
  const bf16* kbase = Kh + ((long long)b * SK + lrow) * HD + lcol;
  const bf16* vbase = Vt + ((long long)b * HD + lrow) * SK + lcol;
  {  // stage main tile 0 into buf1 (last mem iter read buf0; buf1 idle)
    bf16x8 k0 = *(const bf16x8*)kbase;
    bf16x8 k1 = *(const bf16x8*)(kbase + 8);
    bf16x8 v0 = *(const bf16x8*)vbase;
    bf16x8 v1 = *(const bf16x8*)(vbase + 8);
    *(bf16x8*)&Kd[1][lrow][lcol] = k0;
    *(bf16x8*)&Kd[1][lrow][lcol + 8] = k1;
    *(bf16x8*)&Vd[1][lrow][lcol] = v0;
    *(bf16x8*)&Vd[1][lrow][lcol + 8] = v1;
  }
  __syncthreads();
  cur = 1;
  for (int st = 0; st < 16; ++st) {
    bf16x8 kr0, kr1, vr0, vr1;
    if (st < 15) {
      const bf16* kp = kbase + (long long)((st + 1) << 6) * HD;
      const bf16* vp = vbase + ((st + 1) << 6);
      kr0 = *(const bf16x8*)kp;
      kr1 = *(const bf16x8*)(kp + 8);
      vr0 = *(const bf16x8*)vp;
      vr1 = *(const bf16x8*)(vp + 8);
    }
    f32x4 s00 = zero, s01 = zero, s10 = zero, s11 = zero;
    __builtin_amdgcn_s_setprio(1);
#pragma unroll
    for (int kh = 0; kh < 2; ++kh) {
      bf16x8 ak0 = *(bf16x8*)&Kd[cur][wn + m16][(kh << 5) + (quad << 3)];
      bf16x8 ak1 = *(bf16x8*)&Kd[cur][wn + 16 + m16][(kh << 5) + (quad << 3)];
      s00 = MFMA(ak0, aq[0][kh], s00);
      s01 = MFMA(ak0, aq[1][kh], s01);
      s10 = MFMA(ak1, aq[0][kh], s10);
      s11 = MFMA(ak1, aq[1][kh], s11);
    }
    __builtin_amdgcn_s_setprio(0);
    {
      char* pA = (char*)Ps + (wm + m16) * 128;
      char* pB = (char*)Ps + (wm + 16 + m16) * 128;
#pragma unroll
      for (int si = 0; si < 2; ++si) {
        int sloc = wn + (si << 4) + (quad << 2);
        f32x4 rc4 = *(const f32x4*)&rcs[(st << 6) + sloc];
        f32x4 sA = si ? s10 : s00;
        f32x4 sB = si ? s11 : s01;
        __bf16 vA[4], vB[4];
#pragma unroll
        for (int r = 0; r < 4; ++r) {
          float pa = exp2n(sA[r]) * rc4[r];
          rsa[0] += pa; vA[r] = tobf(pa);
          float pb = exp2n(sB[r]) * rc4[r];
          rsa[1] += pb; vB[r] = tobf(pb);
        }
        int sbyte = (sloc << 1) ^ swz;
        *(uint2*)(pA + sbyte) = *(uint2*)vA;
        *(uint2*)(pB + sbyte) = *(uint2*)vB;
      }
    }
    __syncthreads();   // B2
    if (st < 15) {
      *(bf16x8*)&Kd[cur ^ 1][lrow][lcol] = kr0;
      *(bf16x8*)&Kd[cur ^ 1][lrow][lcol + 8] = kr1;
      *(bf16x8*)&Vd[cur ^ 1][lrow][lcol] = vr0;
      *(bf16x8*)&Vd[cur ^ 1][lrow][lcol + 8] = vr1;
    }
    __builtin_amdgcn_s_setprio(1);
#pragma unroll
    for (int kh = 0; kh < 2; ++kh) {
      int sb = (kh << 6) + (quad << 4);
      bf16x8 ap0 = *(bf16x8*)((char*)Ps + (wm + m16) * 128 + (sb ^ swz));
      bf16x8 ap1 = *(bf16x8*)((char*)Ps + (wm + 16 + m16) * 128 + (sb ^ swz));
      bf16x8 bv0 = *(bf16x8*)&Vd[cur][wn + m16][(kh << 5) + (quad << 3)];
      bf16x8 bv1 = *(bf16x8*)&Vd[cur][wn + 16 + m16][(kh << 5) + (quad << 3)];
      o00 = MFMA(ap0, bv0, o00);
      o01 = MFMA(ap0, bv1, o01);
      o10 = MFMA(ap1, bv0, o10);
      o11 = MFMA(ap1, bv1, o11);
    }
    __builtin_amdgcn_s_setprio(0);
    __syncthreads();   // B3
    cur ^= 1;
  }

  // ---------------- reductions (both branches) ----------------
#pragma unroll
  for (int li = 0; li < 2; ++li) {
    float va = rsa[li];
    va += __shfl_xor(va, 16, 64);
    va += __shfl_xor(va, 32, 64);
    float vm = rsm[li];
    vm += __shfl_xor(vm, 16, 64);
    vm += __shfl_xor(vm, 32, 64);
    if (quad == 0) {
      rpa[wm + (li << 4) + m16][wn >> 5] = va;
      rpm[wm + (li << 4) + m16][wn >> 5] = vm;
    }
  }
  __syncthreads();

  // ---------------- gate combine in f32, single bf16 write ----------------
  const float* vs = Vsum + b * HD;
  const float g = 1.f / (1.f + __expf(-gate[h]));
  f32x4 oacc[2][2] = {{o00, o01}, {o10, o11}};
  f32x4 macc[2][2] = {{m00, m01}, {m10, m11}};
  for (int mi = 0; mi < 2; ++mi)
    for (int ni = 0; ni < 2; ++ni) {
      int col = wn + (ni << 4) + m16;
      float vsc = 1e-8f * vs[col];
      for (int r = 0; r < 4; ++r) {
        int row = wm + (mi << 4) + (quad << 2) + r;
        float ra = rpa[row][0] + rpa[row][1];
        float rm = rpm[row][0] + rpm[row][1];
        float oa = (oacc[mi][ni][r] + vsc) / (ra + (float)SK * 1e-8f);
        float om = macc[mi][ni][r] / rm;
        Kd[0][row][col] = tobf(g * om + (1.f - g) * oa);
      }
    }
  __syncthreads();
  uint4 u0 = *(uint4*)&Kd[0][lrow][lcol];
  uint4 u1 = *(uint4*)&Kd[0][lrow][lcol + 8];
  long long gb = ((long long)b * LQ + tm0 + lrow) * HD + lcol;
  *(uint4*)(comb + gb) = u0;
  *(uint4*)(comb + gb + 8) = u1;
}

// ================= out proj, m97-structure (A = fused comb buffer) ===============
__global__ __launch_bounds__(256) void gemm_out(
    const bf16* __restrict__ comb, const bf16* __restrict__ opwb,
    const float* __restrict__ opb, float* __restrict__ out)
{
  __shared__ __align__(16) char smem[32768];
  __bf16* As = (__bf16*)smem;             // [128][64] linear
  __bf16* Bs = (__bf16*)(smem + 16384);   // [128][64] linear
  const int bid2 = blockIdx.y * gridDim.x + blockIdx.x;  // 0..255
  const int xcd = bid2 & 7, sub = bid2 >> 3;             // sub in [0,32)
  const int by = (xcd << 3) + (sub >> 2);                // 0..63
  const int bx = sub & 3;                                // 0..3
  const int tm0 = by << 7, tn0 = bx << 7;
  const int t = threadIdx.x;
  const int wave = t >> 6, lane = t & 63;
  const int wrow0 = (wave & 1) << 6, wcol0 = (wave >> 1) << 6;
  const int m16 = lane & 15, quad = lane >> 4;

  const f32x4 zero = {0.f, 0.f, 0.f, 0.f};
  f32x4 acc[4][4];
#pragma unroll
  for (int mi = 0; mi < 4; ++mi)
#pragma unroll
    for (int ni = 0; ni < 4; ++ni) acc[mi][ni] = zero;

  const bf16* Bb = opwb + (long long)tn0 * EE;
  const int ob_u = wave << 10;

  for (int k0 = 0; k0 < EE; k0 += 64) {
    const int h = k0 >> 6;
#pragma unroll
    for (int c = 0; c < 4; ++c) {
      int ob = (c << 12) + ob_u;
      int obl = ob + (lane << 4);
      int row = obl >> 7;
      int ce = (obl & 127) >> 1;
      int arow = tm0 + row;
      int l = arow >> 3, nn = arow & 7;
      gload_lds16(comb + (((long long)(nn * NH + h) * LQ + l) * HD + ce),
                  smem + ob);
      gload_lds16(Bb + (long long)row * EE + k0 + ce, smem + 16384 + ob);
    }
    __syncthreads();
#pragma unroll
    for (int kh = 0; kh < 2; ++kh) {
      bf16x8 av[4], bv[4];
#pragma unroll
      for (int i = 0; i < 4; ++i) {
        av[i] = *(bf16x8*)(As + ((wrow0 + (i << 4) + m16) << 6) + (kh << 5) + (quad << 3));
        bv[i] = *(bf16x8*)(Bs + ((wcol0 + (i << 4) + m16) << 6) + (kh << 5) + (quad << 3));
      }
#pragma unroll
      for (int mi = 0; mi < 4; ++mi)
#pragma unroll
        for (int ni = 0; ni < 4; ++ni)
          acc[mi][ni] = MFMA(av[mi], bv[ni], acc[mi][ni]);
    }
    __syncthreads();
  }

#pragma unroll
  for (int mi = 0; mi < 4; ++mi)
#pragma unroll
    for (int ni = 0; ni < 4; ++ni) {
      int col = tn0 + wcol0 + (ni << 4) + m16;
      float bv = opb[col];
      int row0 = tm0 + wrow0 + (mi << 4) + (quad << 2);
#pragma unroll
      for (int r = 0; r < 4; ++r)
        out[(long long)(row0 + r) * EE + col] = acc[mi][ni][r] + bv;
    }
}

extern "C" void kernel_launch(void* const* d_in, const int* in_sizes, int n_in,
                              void* d_out, int out_size, void* d_ws, size_t ws_size,
                              hipStream_t stream) {
  const float* query = (const float*)d_in[0];
  const float* key   = (const float*)d_in[1];
  const float* value = (const float*)d_in[2];
  const float* ipw   = (const float*)d_in[3];
  const float* ipb   = (const float*)d_in[4];
  const float* opw   = (const float*)d_in[5];
  const float* opb   = (const float*)d_in[6];
  const float* rot_q = (const float*)d_in[7];
  const float* rot_k = (const float*)d_in[8];
  const float* k_mem = (const float*)d_in[9];
  const float* v_mem = (const float*)d_in[10];
  const float* gate  = (const float*)d_in[11];
  const int*  mask   = (const int*)d_in[12];
  float* out = (float*)d_out;

  char* w = (char*)d_ws;
  size_t off = 0;
  auto carve = [&](size_t bytes) -> char* {
    char* p = w + off;
    off += (bytes + 255) & ~(size_t)255;
    return p;
  };
  bf16* qc    = (bf16*)carve((size_t)LQ * NB * EE * 2);
  bf16* kc    = (bf16*)carve((size_t)SK * NB * EE * 2);
  bf16* vc    = (bf16*)carve((size_t)SK * NB * EE * 2);
  bf16* ipwb  = (bf16*)carve((size_t)3 * EE * EE * 2);
  bf16* opwb  = (bf16*)carve((size_t)EE * EE * 2);
  bf16* v_raw = (bf16*)carve((size_t)SK * NB * EE * 2);
  bf16* Qh    = (bf16*)carve((size_t)NBH * LQ * HD * 2);
  bf16* Kh    = (bf16*)carve((size_t)NBH * SK * HD * 2);
  bf16* Vt    = (bf16*)carve((size_t)NBH * HD * SK * 2);
  bf16* km    = (bf16*)carve((size_t)NBH * MMEM * HD * 2);
  bf16* vmt   = (bf16*)carve((size_t)NBH * HD * MMEM * 2);
  float* csum = (float*)carve((size_t)NBH * SK * 4);
  float* Vsum = (float*)carve((size_t)NBH * HD * 4);
  bf16* comb  = (bf16*)carve((size_t)NBH * LQ * HD * 2);
  bf16* pkbuf = (bf16*)carve((size_t)NBH * LQ * HD * 2);
  if (off > ws_size) {
    hipMemsetAsync(d_out, 0, (size_t)out_size * 4, stream);
    return;
  }
  // pq aliases comb: comb is only written by attn_fused, well after rotary
  // consumed pq. pkbuf is rotary's K staging.
  bf16* pq = comb;
  bf16* pk = pkbuf;

  // 0) pre-convert GEMM inputs to bf16 (also zeroes Vsum; 1 node)
  convert5<<<(3 * CVT_T0 + CVT_T3 + CVT_T4) / 256, 256, 0, stream>>>(
      query, key, value, ipw, opw, qc, kc, vc, ipwb, opwb, Vsum);

  // 1) q/k/v projections (q alpha folds log2e for exp2 softmax downstream)
  gemm_proj3<<<dim3(EE / 128, (LQ * NB) / 128, 3), 256, 0, stream>>>(
      qc, kc, vc, ipwb, ipb, pq, pk, v_raw);

  // 2) merged prep: rotary + v_transpose(+Vsum) + mem_prep (1 node, was 3)
  prep_all<<<4096 + 1024 + 256, 256, 0, stream>>>(
      pq, pk, rot_q, rot_k, Qh, Kh, v_raw, Vt, Vsum, k_mem, v_mem, km, vmt);

  // 3) column sums (128 cols/block, gload_lds Q-dbuf, 1 barrier/iter, exp2)
  colsum_kernel<<<dim3(SK / 128, NBH), 256, 0, stream>>>(Qh, Kh, csum);

  // 4) fused flash (round-6 structure: K/V reg-dbuf, 2 barriers/iter, exp2)
  attn_fused<<<dim3(LQ / 64, NBH), 256, 0, stream>>>(
      Qh, Kh, Vt, km, vmt, csum, Vsum, mask, gate, comb);

  // 5) out-proj, m97 structure, single A buffer
  gemm_out<<<dim3(4, 64), 256, 0, stream>>>(comb, opwb, opb, out);
}